// Round 9
// baseline (519.565 us; speedup 1.0000x reference)
//
#include <hip/hip_runtime.h>
#include <cstdint>
#include <cstddef>

#define NPTS 8192
#define BATCH 16
#define MS 128
#define KNB 64
#define NBLK (BATCH * MS)   // 2048

// ---------------- DPP wave reductions (VALU-speed, no LDS crossbar) ----------
// Sequences per LLVM AMDGPUAtomicOptimizer gfx9: row_shr 1,2,4,8 then
// row_bcast15 (rm 0xa), row_bcast31 (rm 0xc); result valid in lane 63.
// Row variants (row_shr 1,2,4,8): result valid in lane 15 of each row.

__device__ __forceinline__ float dpp_wave_max_f32(float v) {
  v = fmaxf(v, __int_as_float(__builtin_amdgcn_update_dpp((int)0xff800000, __float_as_int(v), 0x111, 0xf, 0xf, false)));
  v = fmaxf(v, __int_as_float(__builtin_amdgcn_update_dpp((int)0xff800000, __float_as_int(v), 0x112, 0xf, 0xf, false)));
  v = fmaxf(v, __int_as_float(__builtin_amdgcn_update_dpp((int)0xff800000, __float_as_int(v), 0x114, 0xf, 0xf, false)));
  v = fmaxf(v, __int_as_float(__builtin_amdgcn_update_dpp((int)0xff800000, __float_as_int(v), 0x118, 0xf, 0xf, false)));
  v = fmaxf(v, __int_as_float(__builtin_amdgcn_update_dpp((int)0xff800000, __float_as_int(v), 0x142, 0xa, 0xf, false)));
  v = fmaxf(v, __int_as_float(__builtin_amdgcn_update_dpp((int)0xff800000, __float_as_int(v), 0x143, 0xc, 0xf, false)));
  return v;  // lane 63
}

__device__ __forceinline__ float dpp_wave_min_f32(float v) {
  v = fminf(v, __int_as_float(__builtin_amdgcn_update_dpp(0x7f800000, __float_as_int(v), 0x111, 0xf, 0xf, false)));
  v = fminf(v, __int_as_float(__builtin_amdgcn_update_dpp(0x7f800000, __float_as_int(v), 0x112, 0xf, 0xf, false)));
  v = fminf(v, __int_as_float(__builtin_amdgcn_update_dpp(0x7f800000, __float_as_int(v), 0x114, 0xf, 0xf, false)));
  v = fminf(v, __int_as_float(__builtin_amdgcn_update_dpp(0x7f800000, __float_as_int(v), 0x118, 0xf, 0xf, false)));
  v = fminf(v, __int_as_float(__builtin_amdgcn_update_dpp(0x7f800000, __float_as_int(v), 0x142, 0xa, 0xf, false)));
  v = fminf(v, __int_as_float(__builtin_amdgcn_update_dpp(0x7f800000, __float_as_int(v), 0x143, 0xc, 0xf, false)));
  return v;  // lane 63
}

__device__ __forceinline__ unsigned dpp_wave_min_u32(unsigned v) {
  unsigned o;
  o = (unsigned)__builtin_amdgcn_update_dpp((int)0xffffffffu, (int)v, 0x111, 0xf, 0xf, false); v = (o < v) ? o : v;
  o = (unsigned)__builtin_amdgcn_update_dpp((int)0xffffffffu, (int)v, 0x112, 0xf, 0xf, false); v = (o < v) ? o : v;
  o = (unsigned)__builtin_amdgcn_update_dpp((int)0xffffffffu, (int)v, 0x114, 0xf, 0xf, false); v = (o < v) ? o : v;
  o = (unsigned)__builtin_amdgcn_update_dpp((int)0xffffffffu, (int)v, 0x118, 0xf, 0xf, false); v = (o < v) ? o : v;
  o = (unsigned)__builtin_amdgcn_update_dpp((int)0xffffffffu, (int)v, 0x142, 0xa, 0xf, false); v = (o < v) ? o : v;
  o = (unsigned)__builtin_amdgcn_update_dpp((int)0xffffffffu, (int)v, 0x143, 0xc, 0xf, false); v = (o < v) ? o : v;
  return v;  // lane 63
}

__device__ __forceinline__ float dpp_row_max_f32(float v) {  // lane 15 of each row
  v = fmaxf(v, __int_as_float(__builtin_amdgcn_update_dpp((int)0xff800000, __float_as_int(v), 0x111, 0xf, 0xf, false)));
  v = fmaxf(v, __int_as_float(__builtin_amdgcn_update_dpp((int)0xff800000, __float_as_int(v), 0x112, 0xf, 0xf, false)));
  v = fmaxf(v, __int_as_float(__builtin_amdgcn_update_dpp((int)0xff800000, __float_as_int(v), 0x114, 0xf, 0xf, false)));
  v = fmaxf(v, __int_as_float(__builtin_amdgcn_update_dpp((int)0xff800000, __float_as_int(v), 0x118, 0xf, 0xf, false)));
  return v;
}

__device__ __forceinline__ unsigned dpp_row_min_u32(unsigned v) {  // lane 15 of each row
  unsigned o;
  o = (unsigned)__builtin_amdgcn_update_dpp((int)0xffffffffu, (int)v, 0x111, 0xf, 0xf, false); v = (o < v) ? o : v;
  o = (unsigned)__builtin_amdgcn_update_dpp((int)0xffffffffu, (int)v, 0x112, 0xf, 0xf, false); v = (o < v) ? o : v;
  o = (unsigned)__builtin_amdgcn_update_dpp((int)0xffffffffu, (int)v, 0x114, 0xf, 0xf, false); v = (o < v) ? o : v;
  o = (unsigned)__builtin_amdgcn_update_dpp((int)0xffffffffu, (int)v, 0x118, 0xf, 0xf, false); v = (o < v) ? o : v;
  return v;
}

__device__ __forceinline__ float dpp_quad_min_f32(float v) {  // lane 3 of each row (4 slots)
  v = fminf(v, __int_as_float(__builtin_amdgcn_update_dpp(0x7f800000, __float_as_int(v), 0x111, 0xf, 0xf, false)));
  v = fminf(v, __int_as_float(__builtin_amdgcn_update_dpp(0x7f800000, __float_as_int(v), 0x112, 0xf, 0xf, false)));
  return v;
}

__device__ __forceinline__ unsigned dpp_quad_min_u32(unsigned v) {  // lane 3
  unsigned o;
  o = (unsigned)__builtin_amdgcn_update_dpp((int)0xffffffffu, (int)v, 0x111, 0xf, 0xf, false); v = (o < v) ? o : v;
  o = (unsigned)__builtin_amdgcn_update_dpp((int)0xffffffffu, (int)v, 0x112, 0xf, 0xf, false); v = (o < v) ? o : v;
  return v;
}

// ---------------------------------------------------------------- FPS
// One block per batch, 1024 threads x 8 pts. STATE-MINIMAL version: rounds
// 4/6/7/8 all hit ~2980cyc/iter at ~82% active-CU VALUBusy regardless of
// structure -- the 32-float X/Y/Z/md register state was being copied through
// AGPR/scratch every iteration (~2x instruction inflation) and no source-level
// trick stopped it. Fix: loop-carried state is ONLY md0..7 (8 regs); X/Y/Z are
// re-read from LDS SoA each iteration (stride-1 b32 per wave = 2 lanes/bank =
// conflict-free; LDS pipe overlaps VALU). DPP reduce + one barrier unchanged
// from round 8 (HW-verified selection semantics). Distance op order unchanged
// (contract off) => identical selections.
#define FPS_STEP(J)                                                        \
  {                                                                        \
    const int i = J * 1024 + t;                                            \
    const float dx = px[i] - lx;                                           \
    const float dy = py[i] - ly;                                           \
    const float dz = pz[i] - lz;                                           \
    const float d = dx * dx + dy * dy + dz * dz;                           \
    md##J = fminf(md##J, d);                                               \
  }

#define FPS_RESCAN(J)                                                      \
  if (md##J == wv) best = (unsigned)(J * 1024 + t);

__global__ __launch_bounds__(1024, 4) void fps_kernel(const float* __restrict__ pos,
                                                      float* __restrict__ sp) {
#pragma clang fp contract(off)
  extern __shared__ float smem[];  // 3 * 8192 floats = 96KB dynamic
  float* px = smem;
  float* py = smem + NPTS;
  float* pz = smem + 2 * NPTS;
  __shared__ float wval[2][16];
  __shared__ unsigned widx[2][16];
  const int b = blockIdx.x;
  const float* P = pos + (size_t)b * NPTS * 3;
  const int t = threadIdx.x;
  const int wave = t >> 6;
  const int lane = t & 63;
  float md0 = 1e10f, md1 = 1e10f, md2 = 1e10f, md3 = 1e10f;
  float md4 = 1e10f, md5 = 1e10f, md6 = 1e10f, md7 = 1e10f;
  for (int i = t; i < NPTS; i += 1024) {
    px[i] = P[i * 3 + 0];
    py[i] = P[i * 3 + 1];
    pz[i] = P[i * 3 + 2];
  }
  float lx = P[0], ly = P[1], lz = P[2];
  __syncthreads();
  for (int it = 0; it < MS; ++it) {
    if (t == 0) {
      sp[((size_t)b * MS + it) * 3 + 0] = lx;
      sp[((size_t)b * MS + it) * 3 + 1] = ly;
      sp[((size_t)b * MS + it) * 3 + 2] = lz;
    }
    FPS_STEP(0) FPS_STEP(1) FPS_STEP(2) FPS_STEP(3)
    FPS_STEP(4) FPS_STEP(5) FPS_STEP(6) FPS_STEP(7)
    // per-thread max over md (depth-3 tree; max is exactly associative)
    const float m01 = fmaxf(md0, md1), m23 = fmaxf(md2, md3);
    const float m45 = fmaxf(md4, md5), m67 = fmaxf(md6, md7);
    const float bv = fmaxf(fmaxf(m01, m23), fmaxf(m45, m67));
    // wave max value (DPP) -> uniform via readlane 63
    const float wv = __int_as_float(
        __builtin_amdgcn_readlane(__float_as_int(dpp_wave_max_f32(bv)), 63));
    // tie threads resolve smallest flat idx (descending J -> smallest wins)
    unsigned best = 0xffffffffu;
    if (bv == wv) {
      FPS_RESCAN(7) FPS_RESCAN(6) FPS_RESCAN(5) FPS_RESCAN(4)
      FPS_RESCAN(3) FPS_RESCAN(2) FPS_RESCAN(1) FPS_RESCAN(0)
    }
    const unsigned wi =
        (unsigned)__builtin_amdgcn_readlane((int)dpp_wave_min_u32(best), 63);
    const int par = it & 1;
    if (lane == 0) { wval[par][wave] = wv; widx[par][wave] = wi; }
    __syncthreads();
    // block fold over 16 wave slots (DPP row reduce), then coord broadcast
    const float a = wval[par][lane & 15];
    const float M = __int_as_float(
        __builtin_amdgcn_readlane(__float_as_int(dpp_row_max_f32(a)), 15));
    const unsigned c2 = (a == M) ? widx[par][lane & 15] : 0xffffffffu;
    const unsigned idx =
        (unsigned)__builtin_amdgcn_readlane((int)dpp_row_min_u32(c2), 15);
    lx = px[idx];  // same addr across lanes -> LDS broadcast
    ly = py[idx];
    lz = pz[idx];
  }
}

// ---------------------------------------------------------------- kNN top-64
// Tournament selection, candidates in registers, DPP reductions, ONE barrier
// per round. Selection order: min distance, tie -> smaller index == exactly
// lax.top_k's stable selection set (proven semantics from earlier rounds).
__global__ __launch_bounds__(256) void knn_kernel(const float* __restrict__ pos,
                                                  const float* __restrict__ xf,
                                                  const float* __restrict__ sp,
                                                  float* __restrict__ gf0,
                                                  float* __restrict__ sqsel) {
#pragma clang fp contract(off)
  __shared__ float sqv[NPTS];
  __shared__ float wval[2][4];
  __shared__ unsigned widx[2][4];
  __shared__ int sel_i[KNB];
  __shared__ float sel_v[KNB];
  const int bm = blockIdx.x;
  const int b = bm >> 7;
  const float* P = pos + (size_t)b * NPTS * 3;
  const float sx = sp[bm * 3 + 0], sy = sp[bm * 3 + 1], sz = sp[bm * 3 + 2];
  const float nsp = sx * sx + sy * sy + sz * sz;
  const int t = threadIdx.x;
  const int wave = t >> 6;
  const int lane = t & 63;
  for (int j = 0; j < 32; ++j) {
    const int i = j * 256 + t;
    const float qx = P[i * 3 + 0], qy = P[i * 3 + 1], qz = P[i * 3 + 2];
    const float npos = qx * qx + qy * qy + qz * qz;
    const float dt = sx * qx + sy * qy + sz * qz;
    float sq = (nsp + npos) - 2.0f * dt;  // matches ||a||^2+||b||^2-2ab order
    sq = fmaxf(sq, 0.0f);
    sqv[i] = sq;
  }
  __syncthreads();
  // per-thread candidate (value, idx) over its 32-element column, in registers
  float cv;
  unsigned ci;
  {
    unsigned long long k0 = ~0ULL;
    for (int j = 0; j < 32; ++j) {
      const int i = j * 256 + t;
      const unsigned long long key =
          ((unsigned long long)__float_as_uint(sqv[i]) << 32) | (unsigned)i;
      if (key < k0) k0 = key;
    }
    cv = __uint_as_float((unsigned)(k0 >> 32));
    ci = (unsigned)k0;
  }
  for (int round = 0; round < KNB; ++round) {
    // wave min (value), tie -> min idx
    const float wv = __int_as_float(
        __builtin_amdgcn_readlane(__float_as_int(dpp_wave_min_f32(cv)), 63));
    const unsigned sel = (cv == wv) ? ci : 0xffffffffu;
    const unsigned wi =
        (unsigned)__builtin_amdgcn_readlane((int)dpp_wave_min_u32(sel), 63);
    const int par = round & 1;
    if (lane == 0) { wval[par][wave] = wv; widx[par][wave] = wi; }
    __syncthreads();
    // block fold over 4 wave slots
    const float a = wval[par][lane & 3];
    const float M = __int_as_float(
        __builtin_amdgcn_readlane(__float_as_int(dpp_quad_min_f32(a)), 3));
    const unsigned c2 = (a == M) ? widx[par][lane & 3] : 0xffffffffu;
    const unsigned idx =
        (unsigned)__builtin_amdgcn_readlane((int)dpp_quad_min_u32(c2), 3);
    const int col = (int)(idx & 255u);
    if (t == col) {
      sel_i[round] = (int)idx;
      sel_v[round] = M;
      sqv[idx] = __uint_as_float(0x7f800000u);  // consumed (visible next round)
    }
    // winner's wave rescans the consumed column (consumed elem masked locally)
    if (wave == (col >> 6)) {
      float v = __uint_as_float(0x7f800000u);
      unsigned ii = 0xffffffffu;
      if (lane < 32) {
        const int i = lane * 256 + col;
        v = sqv[i];
        if (i == (int)idx) v = __uint_as_float(0x7f800000u);
        ii = (unsigned)i;
      }
      const float mv = __int_as_float(
          __builtin_amdgcn_readlane(__float_as_int(dpp_wave_min_f32(v)), 63));
      const unsigned s2 = (v == mv) ? ii : 0xffffffffu;
      const unsigned mi =
          (unsigned)__builtin_amdgcn_readlane((int)dpp_wave_min_u32(s2), 63);
      if (t == col) { cv = mv; ci = mi; }
    }
  }
  __syncthreads();
  if (t < KNB) {
    const int i = sel_i[t];
    const float* X = xf + (size_t)b * NPTS * 3;
    const size_t base = ((size_t)bm * KNB + t) * 6;
    gf0[base + 0] = P[i * 3 + 0] - sx;
    gf0[base + 1] = P[i * 3 + 1] - sy;
    gf0[base + 2] = P[i * 3 + 2] - sz;
    gf0[base + 3] = X[i * 3 + 0];
    gf0[base + 4] = X[i * 3 + 1];
    gf0[base + 5] = X[i * 3 + 2];
    sqsel[(size_t)bm * KNB + t] = sel_v[t];
  }
}

// ---------------------------------------------------------------- stage-0 conv chain
// One block per (b, sample) 64x6 tile. Recomputes the conv chain to the target
// depth each pass (BN needs global stats between layers; FLOPs are tiny).
// MODE 1: y1 stats   MODE 2: y2 stats   MODE 3: y3 stats (+ optional z2 dump)
// MODE 4: masked max -> x1 (fallback when ws too small for the z2 cache).
// Stats partials are written [channel][block] (coalesced for p_stats).
template <int MODE>
__global__ __launch_bounds__(256) void chain_kernel(
    const float* __restrict__ gf0,
    const float* __restrict__ W0, const float* __restrict__ B0,
    const float* __restrict__ W1, const float* __restrict__ B1,
    const float* __restrict__ W2, const float* __restrict__ B2,
    const float* __restrict__ sc1, const float* __restrict__ sh1,
    const float* __restrict__ sc2, const float* __restrict__ sh2,
    const float* __restrict__ sc3, const float* __restrict__ sh3,
    const float* __restrict__ sqsel,
    float* __restrict__ psum, float* __restrict__ psq, float* __restrict__ x1,
    float* __restrict__ z2out) {
  __shared__ float tA[64 * 65];  // +1 pad: kills stride-64 bank conflicts on row reads
  __shared__ float tB[64 * 65];
  __shared__ float wbuf[64 * 64];
  __shared__ float in6[64 * 8];
  __shared__ float sqs[64];
  const int blk = blockIdx.x;
  const int t = threadIdx.x;
  {
    const float* G = gf0 + (size_t)blk * 64 * 6;
    for (int i = t; i < 384; i += 256) in6[(i / 6) * 8 + (i % 6)] = G[i];
    for (int i = t; i < 384; i += 256) wbuf[i] = W0[i];
    if (MODE == 4 && t < 64) sqs[t] = sqsel[(size_t)blk * 64 + t];
  }
  __syncthreads();
  const int r = t >> 2;
  const int c0 = (t & 3) * 16;
  float acc[16];
  // L1: 6 -> 64
#pragma unroll
  for (int j = 0; j < 16; ++j) acc[j] = B0[c0 + j];
  for (int cin = 0; cin < 6; ++cin) {
    const float a = in6[r * 8 + cin];
#pragma unroll
    for (int j = 0; j < 16; ++j) acc[j] = fmaf(a, wbuf[cin * 64 + c0 + j], acc[j]);
  }
  if (MODE == 1) {
#pragma unroll
    for (int j = 0; j < 16; ++j) tA[r * 65 + c0 + j] = acc[j];
    __syncthreads();
    if (t < 64) {
      float s = 0.f, q = 0.f;
      for (int r2 = 0; r2 < 64; ++r2) { const float v = tA[r2 * 65 + t]; s += v; q += v * v; }
      psum[(size_t)t * NBLK + blk] = s;
      psq[(size_t)t * NBLK + blk] = q;
    }
    return;
  }
#pragma unroll
  for (int j = 0; j < 16; ++j) {
    const int c = c0 + j;
    tA[r * 65 + c] = fmaxf(fmaf(acc[j], sc1[c], sh1[c]), 0.f);
  }
  __syncthreads();
  for (int i = t; i < 4096; i += 256) wbuf[i] = W1[i];
  __syncthreads();
  // L2: 64 -> 64
#pragma unroll
  for (int j = 0; j < 16; ++j) acc[j] = B1[c0 + j];
  for (int cin = 0; cin < 64; ++cin) {
    const float a = tA[r * 65 + cin];
    const float4* w4 = reinterpret_cast<const float4*>(&wbuf[cin * 64 + c0]);
#pragma unroll
    for (int k = 0; k < 4; ++k) {
      const float4 w = w4[k];
      acc[k * 4 + 0] = fmaf(a, w.x, acc[k * 4 + 0]);
      acc[k * 4 + 1] = fmaf(a, w.y, acc[k * 4 + 1]);
      acc[k * 4 + 2] = fmaf(a, w.z, acc[k * 4 + 2]);
      acc[k * 4 + 3] = fmaf(a, w.w, acc[k * 4 + 3]);
    }
  }
  if (MODE == 2) {
#pragma unroll
    for (int j = 0; j < 16; ++j) tB[r * 65 + c0 + j] = acc[j];
    __syncthreads();
    if (t < 64) {
      float s = 0.f, q = 0.f;
      for (int r2 = 0; r2 < 64; ++r2) { const float v = tB[r2 * 65 + t]; s += v; q += v * v; }
      psum[(size_t)t * NBLK + blk] = s;
      psq[(size_t)t * NBLK + blk] = q;
    }
    return;
  }
#pragma unroll
  for (int j = 0; j < 16; ++j) {
    const int c = c0 + j;
    tB[r * 65 + c] = fmaxf(fmaf(acc[j], sc2[c], sh2[c]), 0.f);
  }
  // L3: 64 -> 128, processed in channel halves (wbuf holds 64x64 weight half)
  for (int hc = 0; hc < 2; ++hc) {
    __syncthreads();
    for (int i = t; i < 4096; i += 256) {
      const int cin = i >> 6, cc = i & 63;
      wbuf[i] = W2[cin * 128 + hc * 64 + cc];
    }
    if (MODE == 3 && hc == 0 && z2out != nullptr) {
      float* Zg = z2out + (size_t)blk * 4096;
      for (int i = t; i < 4096; i += 256) Zg[i] = tB[(i >> 6) * 65 + (i & 63)];
    }
    __syncthreads();
    float st_s = 0.f, st_q = 0.f, mx = -1e8f;
    for (int rh = 0; rh < 2; ++rh) {
      const int rr = rh * 32 + (t >> 3);
      const int cc0 = (t & 7) * 8;
      float a3[8];
#pragma unroll
      for (int j = 0; j < 8; ++j) a3[j] = B2[hc * 64 + cc0 + j];
      for (int cin = 0; cin < 64; ++cin) {
        const float a = tB[rr * 65 + cin];
        const float4* w4 = reinterpret_cast<const float4*>(&wbuf[cin * 64 + cc0]);
#pragma unroll
        for (int k = 0; k < 2; ++k) {
          const float4 w = w4[k];
          a3[k * 4 + 0] = fmaf(a, w.x, a3[k * 4 + 0]);
          a3[k * 4 + 1] = fmaf(a, w.y, a3[k * 4 + 1]);
          a3[k * 4 + 2] = fmaf(a, w.z, a3[k * 4 + 2]);
          a3[k * 4 + 3] = fmaf(a, w.w, a3[k * 4 + 3]);
        }
      }
      __syncthreads();
#pragma unroll
      for (int j = 0; j < 8; ++j) tA[(t >> 3) * 65 + cc0 + j] = a3[j];
      __syncthreads();
      if (t < 64) {
        if (MODE == 3) {
          for (int q2 = 0; q2 < 32; ++q2) { const float v = tA[q2 * 65 + t]; st_s += v; st_q += v * v; }
        } else {
          const float scv = sc3[hc * 64 + t], shv = sh3[hc * 64 + t];
          for (int q2 = 0; q2 < 32; ++q2) {
            const int kidx = rh * 32 + q2;
            const float y = tA[q2 * 65 + t];
            const float act = fmaxf(fmaf(y, scv, shv), 0.f);
            const float v = (sqs[kidx] <= 0.16f) ? act : -1e8f;
            mx = fmaxf(mx, v);
          }
        }
      }
      __syncthreads();
    }
    if (t < 64) {
      if (MODE == 3) {
        psum[(size_t)(hc * 64 + t) * NBLK + blk] = st_s;
        psq[(size_t)(hc * 64 + t) * NBLK + blk] = st_q;
      } else if (MODE == 4) {
        x1[(size_t)blk * 128 + hc * 64 + t] = mx;
      }
    }
  }
}

// Cached final pass: reads post-BN2 z2 (written by chain<3>), runs only
// L3 + BN3 + radius-masked max. Skips the L1+L2 recompute.
__global__ __launch_bounds__(256) void chain4c_kernel(
    const float* __restrict__ z2, const float* __restrict__ W2, const float* __restrict__ B2,
    const float* __restrict__ sc3, const float* __restrict__ sh3,
    const float* __restrict__ sqsel, float* __restrict__ x1) {
  __shared__ float tA[64 * 65];
  __shared__ float tB[64 * 65];
  __shared__ float wbuf[64 * 64];
  __shared__ float sqs[64];
  const int blk = blockIdx.x;
  const int t = threadIdx.x;
  const float* Zg = z2 + (size_t)blk * 4096;
  for (int i = t; i < 4096; i += 256) tB[(i >> 6) * 65 + (i & 63)] = Zg[i];
  if (t < 64) sqs[t] = sqsel[(size_t)blk * 64 + t];
  for (int hc = 0; hc < 2; ++hc) {
    __syncthreads();
    for (int i = t; i < 4096; i += 256) {
      const int cin = i >> 6, cc = i & 63;
      wbuf[i] = W2[cin * 128 + hc * 64 + cc];
    }
    __syncthreads();
    float mx = -1e8f;
    for (int rh = 0; rh < 2; ++rh) {
      const int rr = rh * 32 + (t >> 3);
      const int cc0 = (t & 7) * 8;
      float a3[8];
#pragma unroll
      for (int j = 0; j < 8; ++j) a3[j] = B2[hc * 64 + cc0 + j];
      for (int cin = 0; cin < 64; ++cin) {
        const float a = tB[rr * 65 + cin];
        const float4* w4 = reinterpret_cast<const float4*>(&wbuf[cin * 64 + cc0]);
#pragma unroll
        for (int k = 0; k < 2; ++k) {
          const float4 w = w4[k];
          a3[k * 4 + 0] = fmaf(a, w.x, a3[k * 4 + 0]);
          a3[k * 4 + 1] = fmaf(a, w.y, a3[k * 4 + 1]);
          a3[k * 4 + 2] = fmaf(a, w.z, a3[k * 4 + 2]);
          a3[k * 4 + 3] = fmaf(a, w.w, a3[k * 4 + 3]);
        }
      }
      __syncthreads();
#pragma unroll
      for (int j = 0; j < 8; ++j) tA[(t >> 3) * 65 + cc0 + j] = a3[j];
      __syncthreads();
      if (t < 64) {
        const float scv = sc3[hc * 64 + t], shv = sh3[hc * 64 + t];
        for (int q2 = 0; q2 < 32; ++q2) {
          const int kidx = rh * 32 + q2;
          const float y = tA[q2 * 65 + t];
          const float act = fmaxf(fmaf(y, scv, shv), 0.f);
          const float v = (sqs[kidx] <= 0.16f) ? act : -1e8f;
          mx = fmaxf(mx, v);
        }
      }
      __syncthreads();
    }
    if (t < 64) x1[(size_t)blk * 128 + hc * 64 + t] = mx;
  }
}

// Parallel deterministic stats reduce: one block per channel, coalesced reads,
// f64 LDS tree.
__global__ __launch_bounds__(256) void p_stats(const float* __restrict__ psum,
                                               const float* __restrict__ psq,
                                               float invN,
                                               const float* __restrict__ g,
                                               const float* __restrict__ be,
                                               float* __restrict__ sc,
                                               float* __restrict__ sh) {
  const int c = blockIdx.x;
  const int t = threadIdx.x;
  double s = 0.0, q = 0.0;
  for (int k = t; k < NBLK; k += 256) {
    s += (double)psum[(size_t)c * NBLK + k];
    q += (double)psq[(size_t)c * NBLK + k];
  }
  __shared__ double ss[256], qq[256];
  ss[t] = s;
  qq[t] = q;
  __syncthreads();
  for (int st = 128; st > 0; st >>= 1) {
    if (t < st) { ss[t] += ss[t + st]; qq[t] += qq[t + st]; }
    __syncthreads();
  }
  if (t == 0) {
    const double mean = ss[0] * (double)invN;
    double var = qq[0] * (double)invN - mean * mean;
    if (var < 0.0) var = 0.0;
    const float scl = (float)((double)g[c] / sqrt(var + 1e-5));
    sc[c] = scl;
    sh[c] = be[c] - (float)mean * scl;
  }
}

// ---------------------------------------------------------------- stage 1 (2048 rows)
__global__ __launch_bounds__(128) void s1_kernel(const float* __restrict__ sp,
                                                 const float* __restrict__ x1,
                                                 const float* __restrict__ W,
                                                 const float* __restrict__ bia,
                                                 float* __restrict__ y1) {
  __shared__ float row[132];
  const int rowid = blockIdx.x;
  const int t = threadIdx.x;
  if (t < 3) row[t] = sp[(size_t)rowid * 3 + t];
  row[3 + t] = x1[(size_t)rowid * 128 + t];
  __syncthreads();
  float acc = bia[t];
  for (int cin = 0; cin < 131; ++cin) acc = fmaf(row[cin], W[(size_t)cin * 128 + t], acc);
  y1[(size_t)rowid * 128 + t] = acc;
}

__global__ __launch_bounds__(128) void s2_kernel(const float* __restrict__ y1,
                                                 const float* __restrict__ sc, const float* __restrict__ sh,
                                                 const float* __restrict__ W, const float* __restrict__ bia,
                                                 float* __restrict__ y2) {
  __shared__ float row[128];
  const int rowid = blockIdx.x;
  const int t = threadIdx.x;
  row[t] = fmaxf(fmaf(y1[(size_t)rowid * 128 + t], sc[t], sh[t]), 0.f);
  __syncthreads();
  float acc = bia[t];
  for (int cin = 0; cin < 128; ++cin) acc = fmaf(row[cin], W[(size_t)cin * 128 + t], acc);
  y2[(size_t)rowid * 128 + t] = acc;
}

__global__ __launch_bounds__(256) void s3_kernel(const float* __restrict__ y2,
                                                 const float* __restrict__ sc, const float* __restrict__ sh,
                                                 const float* __restrict__ W, const float* __restrict__ bia,
                                                 float* __restrict__ y3) {
  __shared__ float row[128];
  const int rowid = blockIdx.x;
  const int t = threadIdx.x;
  if (t < 128) row[t] = fmaxf(fmaf(y2[(size_t)rowid * 128 + t], sc[t], sh[t]), 0.f);
  __syncthreads();
  for (int h = 0; h < 2; ++h) {
    const int c = h * 256 + t;
    float acc = bia[c];
    for (int cin = 0; cin < 128; ++cin) acc = fmaf(row[cin], W[(size_t)cin * 512 + c], acc);
    y3[(size_t)rowid * 512 + c] = acc;
  }
}

// Deterministic per-channel stats over rows (block per channel, tree reduce).
__global__ __launch_bounds__(256) void s_stats(const float* __restrict__ y, int C, int rows,
                                               const float* __restrict__ g, const float* __restrict__ be,
                                               float* __restrict__ sc, float* __restrict__ sh) {
  const int c = blockIdx.x;
  const int t = threadIdx.x;
  double s = 0.0, q = 0.0;
  for (int r2 = t; r2 < rows; r2 += 256) {
    const double v = (double)y[(size_t)r2 * C + c];
    s += v;
    q += v * v;
  }
  __shared__ double ss[256], qq[256];
  ss[t] = s;
  qq[t] = q;
  __syncthreads();
  for (int st = 128; st > 0; st >>= 1) {
    if (t < st) { ss[t] += ss[t + st]; qq[t] += qq[t + st]; }
    __syncthreads();
  }
  if (t == 0) {
    const double mean = ss[0] / rows;
    double var = qq[0] / rows - mean * mean;
    if (var < 0.0) var = 0.0;
    const float scl = (float)((double)g[c] / sqrt(var + 1e-5));
    sc[c] = scl;
    sh[c] = be[c] - (float)mean * scl;
  }
}

__global__ __launch_bounds__(256) void final_kernel(const float* __restrict__ y3,
                                                    const float* __restrict__ sc, const float* __restrict__ sh,
                                                    float* __restrict__ out) {
  const int gid = blockIdx.x * 256 + threadIdx.x;  // 8192 = 16 batches x 512 ch
  const int b = gid >> 9;
  const int c = gid & 511;
  const float scv = sc[c], shv = sh[c];
  float mx = -3.402823466e+38f;
  for (int m = 0; m < 128; ++m) {
    const float v = fmaxf(fmaf(y3[((size_t)(b * 128 + m)) * 512 + c], scv, shv), 0.f);
    mx = fmaxf(mx, v);
  }
  out[gid] = mx;
  if (gid < 48) out[8192 + gid] = 0.f;  // pos_out zeros
}

extern "C" void kernel_launch(void* const* d_in, const int* in_sizes, int n_in,
                              void* d_out, int out_size, void* d_ws, size_t ws_size,
                              hipStream_t stream) {
  const float* x    = (const float*)d_in[0];
  const float* pos  = (const float*)d_in[1];
  const float* W00  = (const float*)d_in[2];
  const float* b00  = (const float*)d_in[3];
  const float* g00  = (const float*)d_in[4];
  const float* be00 = (const float*)d_in[5];
  const float* W01  = (const float*)d_in[6];
  const float* b01  = (const float*)d_in[7];
  const float* g01  = (const float*)d_in[8];
  const float* be01 = (const float*)d_in[9];
  const float* W02  = (const float*)d_in[10];
  const float* b02  = (const float*)d_in[11];
  const float* g02  = (const float*)d_in[12];
  const float* be02 = (const float*)d_in[13];
  const float* W10  = (const float*)d_in[14];
  const float* b10  = (const float*)d_in[15];
  const float* g10  = (const float*)d_in[16];
  const float* be10 = (const float*)d_in[17];
  const float* W11  = (const float*)d_in[18];
  const float* b11  = (const float*)d_in[19];
  const float* g11  = (const float*)d_in[20];
  const float* be11 = (const float*)d_in[21];
  const float* W12  = (const float*)d_in[22];
  const float* b12  = (const float*)d_in[23];
  const float* g12  = (const float*)d_in[24];
  const float* be12 = (const float*)d_in[25];

  float* w = (float*)d_ws;
  float* sp    = w;                  // 16*128*3          = 6144
  float* gf0   = sp + 6144;          // 16*128*64*6       = 786432
  float* sqsel = gf0 + 786432;       // 16*128*64         = 131072
  float* x1    = sqsel + 131072;     // 16*128*128        = 262144
  float* parts = x1 + 262144;        // 128*2048*2        = 524288
  float* psum  = parts;              // [c][blk]
  float* psq   = parts + 128 * NBLK; // [c][blk]
  float* st    = parts + 524288;     // stats area        = 2048
  float* sc1 = st + 0,    *sh1 = st + 64;
  float* sc2 = st + 128,  *sh2 = st + 192;
  float* sc3 = st + 256,  *sh3 = st + 384;
  float* t1sc = st + 512, *t1sh = st + 640;
  float* t2sc = st + 768, *t2sh = st + 896;
  float* t3sc = st + 1024, *t3sh = st + 1536;
  float* y1s = st + 2048;            // 2048*128 = 262144
  float* y2s = y1s + 262144;         // 2048*128 = 262144
  float* y3s = y2s + 262144;         // 2048*512 = 1048576
  const size_t Z2OFF = 3284992;      // end of the base layout (floats)
  const size_t Z2LEN = (size_t)NBLK * 4096;  // 8.39M floats = 33.5MB
  const bool cache_ok = ws_size >= (Z2OFF + Z2LEN) * sizeof(float);
  float* z2 = cache_ok ? (w + Z2OFF) : nullptr;

  fps_kernel<<<BATCH, 1024, 3 * NPTS * sizeof(float), stream>>>(pos, sp);
  knn_kernel<<<BATCH * MS, 256, 0, stream>>>(pos, x, sp, gf0, sqsel);

  const float invN0 = 1.0f / (float)(NBLK * KNB);  // 1/131072
  chain_kernel<1><<<NBLK, 256, 0, stream>>>(gf0, W00, b00, W01, b01, W02, b02,
                                            sc1, sh1, sc2, sh2, sc3, sh3, sqsel, psum, psq, x1, nullptr);
  p_stats<<<64, 256, 0, stream>>>(psum, psq, invN0, g00, be00, sc1, sh1);
  chain_kernel<2><<<NBLK, 256, 0, stream>>>(gf0, W00, b00, W01, b01, W02, b02,
                                            sc1, sh1, sc2, sh2, sc3, sh3, sqsel, psum, psq, x1, nullptr);
  p_stats<<<64, 256, 0, stream>>>(psum, psq, invN0, g01, be01, sc2, sh2);
  chain_kernel<3><<<NBLK, 256, 0, stream>>>(gf0, W00, b00, W01, b01, W02, b02,
                                            sc1, sh1, sc2, sh2, sc3, sh3, sqsel, psum, psq, x1, z2);
  p_stats<<<128, 256, 0, stream>>>(psum, psq, invN0, g02, be02, sc3, sh3);
  if (cache_ok) {
    chain4c_kernel<<<NBLK, 256, 0, stream>>>(z2, W02, b02, sc3, sh3, sqsel, x1);
  } else {
    chain_kernel<4><<<NBLK, 256, 0, stream>>>(gf0, W00, b00, W01, b01, W02, b02,
                                              sc1, sh1, sc2, sh2, sc3, sh3, sqsel, psum, psq, x1, nullptr);
  }

  s1_kernel<<<NBLK, 128, 0, stream>>>(sp, x1, W10, b10, y1s);
  s_stats<<<128, 256, 0, stream>>>(y1s, 128, NBLK, g10, be10, t1sc, t1sh);
  s2_kernel<<<NBLK, 128, 0, stream>>>(y1s, t1sc, t1sh, W11, b11, y2s);
  s_stats<<<128, 256, 0, stream>>>(y2s, 128, NBLK, g11, be11, t2sc, t2sh);
  s3_kernel<<<NBLK, 256, 0, stream>>>(y2s, t2sc, t2sh, W12, b12, y3s);
  s_stats<<<512, 256, 0, stream>>>(y3s, 512, NBLK, g12, be12, t3sc, t3sh);
  final_kernel<<<32, 256, 0, stream>>>(y3s, t3sc, t3sh, (float*)d_out);
}

// Round 10
// 443.178 us; speedup vs baseline: 1.1724x; 1.1724x over previous
//
#include <hip/hip_runtime.h>
#include <cstdint>
#include <cstddef>

#define NPTS 8192
#define BATCH 16
#define MS 128
#define KNB 64
#define NBLK (BATCH * MS)   // 2048

// ---------------- DPP wave reductions (VALU-speed, no LDS crossbar) ----------
__device__ __forceinline__ float dpp_wave_max_f32(float v) {
  v = fmaxf(v, __int_as_float(__builtin_amdgcn_update_dpp((int)0xff800000, __float_as_int(v), 0x111, 0xf, 0xf, false)));
  v = fmaxf(v, __int_as_float(__builtin_amdgcn_update_dpp((int)0xff800000, __float_as_int(v), 0x112, 0xf, 0xf, false)));
  v = fmaxf(v, __int_as_float(__builtin_amdgcn_update_dpp((int)0xff800000, __float_as_int(v), 0x114, 0xf, 0xf, false)));
  v = fmaxf(v, __int_as_float(__builtin_amdgcn_update_dpp((int)0xff800000, __float_as_int(v), 0x118, 0xf, 0xf, false)));
  v = fmaxf(v, __int_as_float(__builtin_amdgcn_update_dpp((int)0xff800000, __float_as_int(v), 0x142, 0xa, 0xf, false)));
  v = fmaxf(v, __int_as_float(__builtin_amdgcn_update_dpp((int)0xff800000, __float_as_int(v), 0x143, 0xc, 0xf, false)));
  return v;  // lane 63
}

__device__ __forceinline__ float dpp_wave_min_f32(float v) {
  v = fminf(v, __int_as_float(__builtin_amdgcn_update_dpp(0x7f800000, __float_as_int(v), 0x111, 0xf, 0xf, false)));
  v = fminf(v, __int_as_float(__builtin_amdgcn_update_dpp(0x7f800000, __float_as_int(v), 0x112, 0xf, 0xf, false)));
  v = fminf(v, __int_as_float(__builtin_amdgcn_update_dpp(0x7f800000, __float_as_int(v), 0x114, 0xf, 0xf, false)));
  v = fminf(v, __int_as_float(__builtin_amdgcn_update_dpp(0x7f800000, __float_as_int(v), 0x118, 0xf, 0xf, false)));
  v = fminf(v, __int_as_float(__builtin_amdgcn_update_dpp(0x7f800000, __float_as_int(v), 0x142, 0xa, 0xf, false)));
  v = fminf(v, __int_as_float(__builtin_amdgcn_update_dpp(0x7f800000, __float_as_int(v), 0x143, 0xc, 0xf, false)));
  return v;  // lane 63
}

__device__ __forceinline__ unsigned dpp_wave_min_u32(unsigned v) {
  unsigned o;
  o = (unsigned)__builtin_amdgcn_update_dpp((int)0xffffffffu, (int)v, 0x111, 0xf, 0xf, false); v = (o < v) ? o : v;
  o = (unsigned)__builtin_amdgcn_update_dpp((int)0xffffffffu, (int)v, 0x112, 0xf, 0xf, false); v = (o < v) ? o : v;
  o = (unsigned)__builtin_amdgcn_update_dpp((int)0xffffffffu, (int)v, 0x114, 0xf, 0xf, false); v = (o < v) ? o : v;
  o = (unsigned)__builtin_amdgcn_update_dpp((int)0xffffffffu, (int)v, 0x118, 0xf, 0xf, false); v = (o < v) ? o : v;
  o = (unsigned)__builtin_amdgcn_update_dpp((int)0xffffffffu, (int)v, 0x142, 0xa, 0xf, false); v = (o < v) ? o : v;
  o = (unsigned)__builtin_amdgcn_update_dpp((int)0xffffffffu, (int)v, 0x143, 0xc, 0xf, false); v = (o < v) ? o : v;
  return v;  // lane 63
}

__device__ __forceinline__ float dpp_row_max_f32(float v) {  // lane 15 of each row
  v = fmaxf(v, __int_as_float(__builtin_amdgcn_update_dpp((int)0xff800000, __float_as_int(v), 0x111, 0xf, 0xf, false)));
  v = fmaxf(v, __int_as_float(__builtin_amdgcn_update_dpp((int)0xff800000, __float_as_int(v), 0x112, 0xf, 0xf, false)));
  v = fmaxf(v, __int_as_float(__builtin_amdgcn_update_dpp((int)0xff800000, __float_as_int(v), 0x114, 0xf, 0xf, false)));
  v = fmaxf(v, __int_as_float(__builtin_amdgcn_update_dpp((int)0xff800000, __float_as_int(v), 0x118, 0xf, 0xf, false)));
  return v;
}

__device__ __forceinline__ unsigned dpp_row_min_u32(unsigned v) {  // lane 15 of each row
  unsigned o;
  o = (unsigned)__builtin_amdgcn_update_dpp((int)0xffffffffu, (int)v, 0x111, 0xf, 0xf, false); v = (o < v) ? o : v;
  o = (unsigned)__builtin_amdgcn_update_dpp((int)0xffffffffu, (int)v, 0x112, 0xf, 0xf, false); v = (o < v) ? o : v;
  o = (unsigned)__builtin_amdgcn_update_dpp((int)0xffffffffu, (int)v, 0x114, 0xf, 0xf, false); v = (o < v) ? o : v;
  o = (unsigned)__builtin_amdgcn_update_dpp((int)0xffffffffu, (int)v, 0x118, 0xf, 0xf, false); v = (o < v) ? o : v;
  return v;
}

__device__ __forceinline__ float dpp_quad_min_f32(float v) {  // lane 3
  v = fminf(v, __int_as_float(__builtin_amdgcn_update_dpp(0x7f800000, __float_as_int(v), 0x111, 0xf, 0xf, false)));
  v = fminf(v, __int_as_float(__builtin_amdgcn_update_dpp(0x7f800000, __float_as_int(v), 0x112, 0xf, 0xf, false)));
  return v;
}

__device__ __forceinline__ unsigned dpp_quad_min_u32(unsigned v) {  // lane 3
  unsigned o;
  o = (unsigned)__builtin_amdgcn_update_dpp((int)0xffffffffu, (int)v, 0x111, 0xf, 0xf, false); v = (o < v) ? o : v;
  o = (unsigned)__builtin_amdgcn_update_dpp((int)0xffffffffu, (int)v, 0x112, 0xf, 0xf, false); v = (o < v) ? o : v;
  return v;
}

// ---------------------------------------------------------------- FPS
// (round-9 version; 5 structures converged to ~160us -> at structural floor)
#define FPS_STEP(J)                                                        \
  {                                                                        \
    const int i = J * 1024 + t;                                            \
    const float dx = px[i] - lx;                                           \
    const float dy = py[i] - ly;                                           \
    const float dz = pz[i] - lz;                                           \
    const float d = dx * dx + dy * dy + dz * dz;                           \
    md##J = fminf(md##J, d);                                               \
  }

#define FPS_RESCAN(J)                                                      \
  if (md##J == wv) best = (unsigned)(J * 1024 + t);

__global__ __launch_bounds__(1024, 4) void fps_kernel(const float* __restrict__ pos,
                                                      float* __restrict__ sp) {
#pragma clang fp contract(off)
  extern __shared__ float smem[];  // 3 * 8192 floats = 96KB dynamic
  float* px = smem;
  float* py = smem + NPTS;
  float* pz = smem + 2 * NPTS;
  __shared__ float wval[2][16];
  __shared__ unsigned widx[2][16];
  const int b = blockIdx.x;
  const float* P = pos + (size_t)b * NPTS * 3;
  const int t = threadIdx.x;
  const int wave = t >> 6;
  const int lane = t & 63;
  float md0 = 1e10f, md1 = 1e10f, md2 = 1e10f, md3 = 1e10f;
  float md4 = 1e10f, md5 = 1e10f, md6 = 1e10f, md7 = 1e10f;
  for (int i = t; i < NPTS; i += 1024) {
    px[i] = P[i * 3 + 0];
    py[i] = P[i * 3 + 1];
    pz[i] = P[i * 3 + 2];
  }
  float lx = P[0], ly = P[1], lz = P[2];
  __syncthreads();
  for (int it = 0; it < MS; ++it) {
    if (t == 0) {
      sp[((size_t)b * MS + it) * 3 + 0] = lx;
      sp[((size_t)b * MS + it) * 3 + 1] = ly;
      sp[((size_t)b * MS + it) * 3 + 2] = lz;
    }
    FPS_STEP(0) FPS_STEP(1) FPS_STEP(2) FPS_STEP(3)
    FPS_STEP(4) FPS_STEP(5) FPS_STEP(6) FPS_STEP(7)
    const float m01 = fmaxf(md0, md1), m23 = fmaxf(md2, md3);
    const float m45 = fmaxf(md4, md5), m67 = fmaxf(md6, md7);
    const float bv = fmaxf(fmaxf(m01, m23), fmaxf(m45, m67));
    const float wv = __int_as_float(
        __builtin_amdgcn_readlane(__float_as_int(dpp_wave_max_f32(bv)), 63));
    unsigned best = 0xffffffffu;
    if (bv == wv) {
      FPS_RESCAN(7) FPS_RESCAN(6) FPS_RESCAN(5) FPS_RESCAN(4)
      FPS_RESCAN(3) FPS_RESCAN(2) FPS_RESCAN(1) FPS_RESCAN(0)
    }
    const unsigned wi =
        (unsigned)__builtin_amdgcn_readlane((int)dpp_wave_min_u32(best), 63);
    const int par = it & 1;
    if (lane == 0) { wval[par][wave] = wv; widx[par][wave] = wi; }
    __syncthreads();
    const float a = wval[par][lane & 15];
    const float M = __int_as_float(
        __builtin_amdgcn_readlane(__float_as_int(dpp_row_max_f32(a)), 15));
    const unsigned c2 = (a == M) ? widx[par][lane & 15] : 0xffffffffu;
    const unsigned idx =
        (unsigned)__builtin_amdgcn_readlane((int)dpp_row_min_u32(c2), 15);
    lx = px[idx];
    ly = py[idx];
    lz = pz[idx];
  }
}

// ---------------------------------------------------------------- kNN top-64
__global__ __launch_bounds__(256) void knn_kernel(const float* __restrict__ pos,
                                                  const float* __restrict__ xf,
                                                  const float* __restrict__ sp,
                                                  float* __restrict__ gf0,
                                                  float* __restrict__ sqsel) {
#pragma clang fp contract(off)
  __shared__ float sqv[NPTS];
  __shared__ float wval[2][4];
  __shared__ unsigned widx[2][4];
  __shared__ int sel_i[KNB];
  __shared__ float sel_v[KNB];
  const int bm = blockIdx.x;
  const int b = bm >> 7;
  const float* P = pos + (size_t)b * NPTS * 3;
  const float sx = sp[bm * 3 + 0], sy = sp[bm * 3 + 1], sz = sp[bm * 3 + 2];
  const float nsp = sx * sx + sy * sy + sz * sz;
  const int t = threadIdx.x;
  const int wave = t >> 6;
  const int lane = t & 63;
  for (int j = 0; j < 32; ++j) {
    const int i = j * 256 + t;
    const float qx = P[i * 3 + 0], qy = P[i * 3 + 1], qz = P[i * 3 + 2];
    const float npos = qx * qx + qy * qy + qz * qz;
    const float dt = sx * qx + sy * qy + sz * qz;
    float sq = (nsp + npos) - 2.0f * dt;  // matches ||a||^2+||b||^2-2ab order
    sq = fmaxf(sq, 0.0f);
    sqv[i] = sq;
  }
  __syncthreads();
  float cv;
  unsigned ci;
  {
    unsigned long long k0 = ~0ULL;
    for (int j = 0; j < 32; ++j) {
      const int i = j * 256 + t;
      const unsigned long long key =
          ((unsigned long long)__float_as_uint(sqv[i]) << 32) | (unsigned)i;
      if (key < k0) k0 = key;
    }
    cv = __uint_as_float((unsigned)(k0 >> 32));
    ci = (unsigned)k0;
  }
  for (int round = 0; round < KNB; ++round) {
    const float wv = __int_as_float(
        __builtin_amdgcn_readlane(__float_as_int(dpp_wave_min_f32(cv)), 63));
    const unsigned sel = (cv == wv) ? ci : 0xffffffffu;
    const unsigned wi =
        (unsigned)__builtin_amdgcn_readlane((int)dpp_wave_min_u32(sel), 63);
    const int par = round & 1;
    if (lane == 0) { wval[par][wave] = wv; widx[par][wave] = wi; }
    __syncthreads();
    const float a = wval[par][lane & 3];
    const float M = __int_as_float(
        __builtin_amdgcn_readlane(__float_as_int(dpp_quad_min_f32(a)), 3));
    const unsigned c2 = (a == M) ? widx[par][lane & 3] : 0xffffffffu;
    const unsigned idx =
        (unsigned)__builtin_amdgcn_readlane((int)dpp_quad_min_u32(c2), 3);
    const int col = (int)(idx & 255u);
    if (t == col) {
      sel_i[round] = (int)idx;
      sel_v[round] = M;
      sqv[idx] = __uint_as_float(0x7f800000u);  // consumed (visible next round)
    }
    if (wave == (col >> 6)) {
      float v = __uint_as_float(0x7f800000u);
      unsigned ii = 0xffffffffu;
      if (lane < 32) {
        const int i = lane * 256 + col;
        v = sqv[i];
        if (i == (int)idx) v = __uint_as_float(0x7f800000u);
        ii = (unsigned)i;
      }
      const float mv = __int_as_float(
          __builtin_amdgcn_readlane(__float_as_int(dpp_wave_min_f32(v)), 63));
      const unsigned s2 = (v == mv) ? ii : 0xffffffffu;
      const unsigned mi =
          (unsigned)__builtin_amdgcn_readlane((int)dpp_wave_min_u32(s2), 63);
      if (t == col) { cv = mv; ci = mi; }
    }
  }
  __syncthreads();
  if (t < KNB) {
    const int i = sel_i[t];
    const float* X = xf + (size_t)b * NPTS * 3;
    const size_t base = ((size_t)bm * KNB + t) * 6;
    gf0[base + 0] = P[i * 3 + 0] - sx;
    gf0[base + 1] = P[i * 3 + 1] - sy;
    gf0[base + 2] = P[i * 3 + 2] - sz;
    gf0[base + 3] = X[i * 3 + 0];
    gf0[base + 4] = X[i * 3 + 1];
    gf0[base + 5] = X[i * 3 + 2];
    sqsel[(size_t)bm * KNB + t] = sel_v[t];
  }
}

// ================================================================ NEW chain
// Single-compute stack with pre-BN activation caching (bit-identical FMA
// order vs the recompute path) + register-tiled GEMMs (4x4 acc/thread,
// float4 A/B reads: 8 ds_read_b128 per 64 FMA vs old 4 per 16).

// L1: 6->64, write y1pre (pre-BN) + stats. Identical arithmetic to chain<1>.
__global__ __launch_bounds__(256) void l1_kernel(
    const float* __restrict__ gf0, const float* __restrict__ W0,
    const float* __restrict__ B0,
    float* __restrict__ psum, float* __restrict__ psq,
    float* __restrict__ y1pre) {
  __shared__ float in6[64 * 8];
  __shared__ float wbuf[384];
  __shared__ float out[64 * 65];
  const int blk = blockIdx.x;
  const int t = threadIdx.x;
  const float* G = gf0 + (size_t)blk * 384;
  for (int i = t; i < 384; i += 256) in6[(i / 6) * 8 + (i % 6)] = G[i];
  for (int i = t; i < 384; i += 256) wbuf[i] = W0[i];
  __syncthreads();
  const int r = t >> 2;
  const int c0 = (t & 3) * 16;
  float acc[16];
#pragma unroll
  for (int j = 0; j < 16; ++j) acc[j] = B0[c0 + j];
  for (int cin = 0; cin < 6; ++cin) {
    const float a = in6[r * 8 + cin];
#pragma unroll
    for (int j = 0; j < 16; ++j) acc[j] = fmaf(a, wbuf[cin * 64 + c0 + j], acc[j]);
  }
#pragma unroll
  for (int j = 0; j < 16; ++j) out[r * 65 + c0 + j] = acc[j];
  __syncthreads();
  if (t < 64) {
    float s = 0.f, q = 0.f;
    for (int r2 = 0; r2 < 64; ++r2) { const float v = out[r2 * 65 + t]; s += v; q += v * v; }
    psum[(size_t)t * NBLK + blk] = s;
    psq[(size_t)t * NBLK + blk] = q;
  }
  float* Y = y1pre + (size_t)blk * 4096;
  for (int i = t; i < 4096; i += 256) Y[i] = out[(i >> 6) * 65 + (i & 63)];
}

// L2: BN1+ReLU on load, 64x64 GEMM (reg-tiled), write y2pre + stats.
// FMA order: acc[row][col] init B1[col] then k=0..63 ascending -- identical
// sequence to old chain<2>.
__global__ __launch_bounds__(256) void l2_kernel(
    const float* __restrict__ ypre, const float* __restrict__ sc,
    const float* __restrict__ sh, const float* __restrict__ W1,
    const float* __restrict__ B1,
    float* __restrict__ psum, float* __restrict__ psq,
    float* __restrict__ yout) {
  __shared__ float As[64 * 68];  // stride 68: 16B-aligned float4 rows
  __shared__ float Bs[64 * 64];
  __shared__ float out[64 * 68];
  const int blk = blockIdx.x;
  const int t = threadIdx.x;
  const float* Y = ypre + (size_t)blk * 4096;
  for (int i = t; i < 4096; i += 256) {
    const int c = i & 63;
    As[(i >> 6) * 68 + c] = fmaxf(fmaf(Y[i], sc[c], sh[c]), 0.f);
  }
  for (int i = t; i < 4096; i += 256) Bs[i] = W1[i];
  __syncthreads();
  const int tr = t >> 4;          // 0..15 row base
  const int tc4 = (t & 15) * 4;   // col base
  float acc[4][4];
#pragma unroll
  for (int s = 0; s < 4; ++s)
#pragma unroll
    for (int j = 0; j < 4; ++j) acc[s][j] = B1[tc4 + j];
  for (int k0 = 0; k0 < 64; k0 += 4) {
    float4 av[4];
#pragma unroll
    for (int s = 0; s < 4; ++s)
      av[s] = *reinterpret_cast<const float4*>(&As[(tr + 16 * s) * 68 + k0]);
#pragma unroll
    for (int kk = 0; kk < 4; ++kk) {
      const float4 bv = *reinterpret_cast<const float4*>(&Bs[(k0 + kk) * 64 + tc4]);
#pragma unroll
      for (int s = 0; s < 4; ++s) {
        const float a = (kk == 0) ? av[s].x : (kk == 1) ? av[s].y
                       : (kk == 2) ? av[s].z : av[s].w;
        acc[s][0] = fmaf(a, bv.x, acc[s][0]);
        acc[s][1] = fmaf(a, bv.y, acc[s][1]);
        acc[s][2] = fmaf(a, bv.z, acc[s][2]);
        acc[s][3] = fmaf(a, bv.w, acc[s][3]);
      }
    }
  }
#pragma unroll
  for (int s = 0; s < 4; ++s) {
    float4 o;
    o.x = acc[s][0]; o.y = acc[s][1]; o.z = acc[s][2]; o.w = acc[s][3];
    *reinterpret_cast<float4*>(&out[(tr + 16 * s) * 68 + tc4]) = o;
  }
  __syncthreads();
  if (t < 64) {
    float s = 0.f, q = 0.f;
    for (int r2 = 0; r2 < 64; ++r2) { const float v = out[r2 * 68 + t]; s += v; q += v * v; }
    psum[(size_t)t * NBLK + blk] = s;
    psq[(size_t)t * NBLK + blk] = q;
  }
  float* O = yout + (size_t)blk * 4096;
  for (int i = t; i < 4096; i += 256) O[i] = out[(i >> 6) * 68 + (i & 63)];
}

// L3: BN2+ReLU on load, 64x128 GEMM in 2 column halves, write y3pre + stats.
__global__ __launch_bounds__(256) void l3_kernel(
    const float* __restrict__ ypre, const float* __restrict__ sc,
    const float* __restrict__ sh, const float* __restrict__ W2,
    const float* __restrict__ B2,
    float* __restrict__ psum, float* __restrict__ psq,
    float* __restrict__ yout) {
  __shared__ float As[64 * 68];
  __shared__ float Bs[64 * 64];
  __shared__ float out[64 * 68];
  const int blk = blockIdx.x;
  const int t = threadIdx.x;
  const float* Y = ypre + (size_t)blk * 4096;
  for (int i = t; i < 4096; i += 256) {
    const int c = i & 63;
    As[(i >> 6) * 68 + c] = fmaxf(fmaf(Y[i], sc[c], sh[c]), 0.f);
  }
  const int tr = t >> 4;
  const int tc4 = (t & 15) * 4;
  for (int hc = 0; hc < 2; ++hc) {
    __syncthreads();  // As ready (hc=0) / prev dump done (hc=1)
    for (int i = t; i < 4096; i += 256)
      Bs[i] = W2[(i >> 6) * 128 + hc * 64 + (i & 63)];
    __syncthreads();
    float acc[4][4];
#pragma unroll
    for (int s = 0; s < 4; ++s)
#pragma unroll
      for (int j = 0; j < 4; ++j) acc[s][j] = B2[hc * 64 + tc4 + j];
    for (int k0 = 0; k0 < 64; k0 += 4) {
      float4 av[4];
#pragma unroll
      for (int s = 0; s < 4; ++s)
        av[s] = *reinterpret_cast<const float4*>(&As[(tr + 16 * s) * 68 + k0]);
#pragma unroll
      for (int kk = 0; kk < 4; ++kk) {
        const float4 bv = *reinterpret_cast<const float4*>(&Bs[(k0 + kk) * 64 + tc4]);
#pragma unroll
        for (int s = 0; s < 4; ++s) {
          const float a = (kk == 0) ? av[s].x : (kk == 1) ? av[s].y
                         : (kk == 2) ? av[s].z : av[s].w;
          acc[s][0] = fmaf(a, bv.x, acc[s][0]);
          acc[s][1] = fmaf(a, bv.y, acc[s][1]);
          acc[s][2] = fmaf(a, bv.z, acc[s][2]);
          acc[s][3] = fmaf(a, bv.w, acc[s][3]);
        }
      }
    }
#pragma unroll
    for (int s = 0; s < 4; ++s) {
      float4 o;
      o.x = acc[s][0]; o.y = acc[s][1]; o.z = acc[s][2]; o.w = acc[s][3];
      *reinterpret_cast<float4*>(&out[(tr + 16 * s) * 68 + tc4]) = o;
    }
    __syncthreads();
    if (t < 64) {
      float s = 0.f, q = 0.f;
      for (int r2 = 0; r2 < 64; ++r2) { const float v = out[r2 * 68 + t]; s += v; q += v * v; }
      psum[(size_t)(hc * 64 + t) * NBLK + blk] = s;
      psq[(size_t)(hc * 64 + t) * NBLK + blk] = q;
    }
    float* O = yout + (size_t)blk * 8192;
    for (int i = t; i < 4096; i += 256)
      O[(i >> 6) * 128 + hc * 64 + (i & 63)] = out[(i >> 6) * 68 + (i & 63)];
  }
}

// L4: BN3+ReLU+radius-mask+max over 64 neighbors -> x1. Row order ascending
// (identical fmaxf chain to old chain<4>/chain4c).
__global__ __launch_bounds__(128) void l4_kernel(
    const float* __restrict__ y3pre, const float* __restrict__ sc3,
    const float* __restrict__ sh3, const float* __restrict__ sqsel,
    float* __restrict__ x1) {
  __shared__ float sqs[64];
  const int blk = blockIdx.x;
  const int t = threadIdx.x;
  if (t < 64) sqs[t] = sqsel[(size_t)blk * 64 + t];
  __syncthreads();
  const float scv = sc3[t], shv = sh3[t];
  const float* Y = y3pre + (size_t)blk * 8192;
  float mx = -1e8f;
  for (int r = 0; r < 64; ++r) {
    const float act = fmaxf(fmaf(Y[r * 128 + t], scv, shv), 0.f);
    const float v = (sqs[r] <= 0.16f) ? act : -1e8f;
    mx = fmaxf(mx, v);
  }
  x1[(size_t)blk * 128 + t] = mx;
}

// ---------------- OLD recompute chain (fallback when ws too small) ----------
template <int MODE>
__global__ __launch_bounds__(256) void chain_kernel(
    const float* __restrict__ gf0,
    const float* __restrict__ W0, const float* __restrict__ B0,
    const float* __restrict__ W1, const float* __restrict__ B1,
    const float* __restrict__ W2, const float* __restrict__ B2,
    const float* __restrict__ sc1, const float* __restrict__ sh1,
    const float* __restrict__ sc2, const float* __restrict__ sh2,
    const float* __restrict__ sc3, const float* __restrict__ sh3,
    const float* __restrict__ sqsel,
    float* __restrict__ psum, float* __restrict__ psq, float* __restrict__ x1) {
  __shared__ float tA[64 * 65];
  __shared__ float tB[64 * 65];
  __shared__ float wbuf[64 * 64];
  __shared__ float in6[64 * 8];
  __shared__ float sqs[64];
  const int blk = blockIdx.x;
  const int t = threadIdx.x;
  {
    const float* G = gf0 + (size_t)blk * 64 * 6;
    for (int i = t; i < 384; i += 256) in6[(i / 6) * 8 + (i % 6)] = G[i];
    for (int i = t; i < 384; i += 256) wbuf[i] = W0[i];
    if (MODE == 4 && t < 64) sqs[t] = sqsel[(size_t)blk * 64 + t];
  }
  __syncthreads();
  const int r = t >> 2;
  const int c0 = (t & 3) * 16;
  float acc[16];
#pragma unroll
  for (int j = 0; j < 16; ++j) acc[j] = B0[c0 + j];
  for (int cin = 0; cin < 6; ++cin) {
    const float a = in6[r * 8 + cin];
#pragma unroll
    for (int j = 0; j < 16; ++j) acc[j] = fmaf(a, wbuf[cin * 64 + c0 + j], acc[j]);
  }
  if (MODE == 1) {
#pragma unroll
    for (int j = 0; j < 16; ++j) tA[r * 65 + c0 + j] = acc[j];
    __syncthreads();
    if (t < 64) {
      float s = 0.f, q = 0.f;
      for (int r2 = 0; r2 < 64; ++r2) { const float v = tA[r2 * 65 + t]; s += v; q += v * v; }
      psum[(size_t)t * NBLK + blk] = s;
      psq[(size_t)t * NBLK + blk] = q;
    }
    return;
  }
#pragma unroll
  for (int j = 0; j < 16; ++j) {
    const int c = c0 + j;
    tA[r * 65 + c] = fmaxf(fmaf(acc[j], sc1[c], sh1[c]), 0.f);
  }
  __syncthreads();
  for (int i = t; i < 4096; i += 256) wbuf[i] = W1[i];
  __syncthreads();
#pragma unroll
  for (int j = 0; j < 16; ++j) acc[j] = B1[c0 + j];
  for (int cin = 0; cin < 64; ++cin) {
    const float a = tA[r * 65 + cin];
    const float4* w4 = reinterpret_cast<const float4*>(&wbuf[cin * 64 + c0]);
#pragma unroll
    for (int k = 0; k < 4; ++k) {
      const float4 w = w4[k];
      acc[k * 4 + 0] = fmaf(a, w.x, acc[k * 4 + 0]);
      acc[k * 4 + 1] = fmaf(a, w.y, acc[k * 4 + 1]);
      acc[k * 4 + 2] = fmaf(a, w.z, acc[k * 4 + 2]);
      acc[k * 4 + 3] = fmaf(a, w.w, acc[k * 4 + 3]);
    }
  }
  if (MODE == 2) {
#pragma unroll
    for (int j = 0; j < 16; ++j) tB[r * 65 + c0 + j] = acc[j];
    __syncthreads();
    if (t < 64) {
      float s = 0.f, q = 0.f;
      for (int r2 = 0; r2 < 64; ++r2) { const float v = tB[r2 * 65 + t]; s += v; q += v * v; }
      psum[(size_t)t * NBLK + blk] = s;
      psq[(size_t)t * NBLK + blk] = q;
    }
    return;
  }
#pragma unroll
  for (int j = 0; j < 16; ++j) {
    const int c = c0 + j;
    tB[r * 65 + c] = fmaxf(fmaf(acc[j], sc2[c], sh2[c]), 0.f);
  }
  for (int hc = 0; hc < 2; ++hc) {
    __syncthreads();
    for (int i = t; i < 4096; i += 256) {
      const int cin = i >> 6, cc = i & 63;
      wbuf[i] = W2[cin * 128 + hc * 64 + cc];
    }
    __syncthreads();
    float st_s = 0.f, st_q = 0.f, mx = -1e8f;
    for (int rh = 0; rh < 2; ++rh) {
      const int rr = rh * 32 + (t >> 3);
      const int cc0 = (t & 7) * 8;
      float a3[8];
#pragma unroll
      for (int j = 0; j < 8; ++j) a3[j] = B2[hc * 64 + cc0 + j];
      for (int cin = 0; cin < 64; ++cin) {
        const float a = tB[rr * 65 + cin];
        const float4* w4 = reinterpret_cast<const float4*>(&wbuf[cin * 64 + cc0]);
#pragma unroll
        for (int k = 0; k < 2; ++k) {
          const float4 w = w4[k];
          a3[k * 4 + 0] = fmaf(a, w.x, a3[k * 4 + 0]);
          a3[k * 4 + 1] = fmaf(a, w.y, a3[k * 4 + 1]);
          a3[k * 4 + 2] = fmaf(a, w.z, a3[k * 4 + 2]);
          a3[k * 4 + 3] = fmaf(a, w.w, a3[k * 4 + 3]);
        }
      }
      __syncthreads();
#pragma unroll
      for (int j = 0; j < 8; ++j) tA[(t >> 3) * 65 + cc0 + j] = a3[j];
      __syncthreads();
      if (t < 64) {
        if (MODE == 3) {
          for (int q2 = 0; q2 < 32; ++q2) { const float v = tA[q2 * 65 + t]; st_s += v; st_q += v * v; }
        } else {
          const float scv = sc3[hc * 64 + t], shv = sh3[hc * 64 + t];
          for (int q2 = 0; q2 < 32; ++q2) {
            const int kidx = rh * 32 + q2;
            const float y = tA[q2 * 65 + t];
            const float act = fmaxf(fmaf(y, scv, shv), 0.f);
            const float v = (sqs[kidx] <= 0.16f) ? act : -1e8f;
            mx = fmaxf(mx, v);
          }
        }
      }
      __syncthreads();
    }
    if (t < 64) {
      if (MODE == 3) {
        psum[(size_t)(hc * 64 + t) * NBLK + blk] = st_s;
        psq[(size_t)(hc * 64 + t) * NBLK + blk] = st_q;
      } else if (MODE == 4) {
        x1[(size_t)blk * 128 + hc * 64 + t] = mx;
      }
    }
  }
}

// Parallel deterministic stats reduce: one block per channel, f64 LDS tree.
__global__ __launch_bounds__(256) void p_stats(const float* __restrict__ psum,
                                               const float* __restrict__ psq,
                                               float invN,
                                               const float* __restrict__ g,
                                               const float* __restrict__ be,
                                               float* __restrict__ sc,
                                               float* __restrict__ sh) {
  const int c = blockIdx.x;
  const int t = threadIdx.x;
  double s = 0.0, q = 0.0;
  for (int k = t; k < NBLK; k += 256) {
    s += (double)psum[(size_t)c * NBLK + k];
    q += (double)psq[(size_t)c * NBLK + k];
  }
  __shared__ double ss[256], qq[256];
  ss[t] = s;
  qq[t] = q;
  __syncthreads();
  for (int st = 128; st > 0; st >>= 1) {
    if (t < st) { ss[t] += ss[t + st]; qq[t] += qq[t + st]; }
    __syncthreads();
  }
  if (t == 0) {
    const double mean = ss[0] * (double)invN;
    double var = qq[0] * (double)invN - mean * mean;
    if (var < 0.0) var = 0.0;
    const float scl = (float)((double)g[c] / sqrt(var + 1e-5));
    sc[c] = scl;
    sh[c] = be[c] - (float)mean * scl;
  }
}

// ---------------------------------------------------------------- stage 1
__global__ __launch_bounds__(128) void s1_kernel(const float* __restrict__ sp,
                                                 const float* __restrict__ x1,
                                                 const float* __restrict__ W,
                                                 const float* __restrict__ bia,
                                                 float* __restrict__ y1) {
  __shared__ float row[132];
  const int rowid = blockIdx.x;
  const int t = threadIdx.x;
  if (t < 3) row[t] = sp[(size_t)rowid * 3 + t];
  row[3 + t] = x1[(size_t)rowid * 128 + t];
  __syncthreads();
  float acc = bia[t];
  for (int cin = 0; cin < 131; ++cin) acc = fmaf(row[cin], W[(size_t)cin * 128 + t], acc);
  y1[(size_t)rowid * 128 + t] = acc;
}

__global__ __launch_bounds__(128) void s2_kernel(const float* __restrict__ y1,
                                                 const float* __restrict__ sc, const float* __restrict__ sh,
                                                 const float* __restrict__ W, const float* __restrict__ bia,
                                                 float* __restrict__ y2) {
  __shared__ float row[128];
  const int rowid = blockIdx.x;
  const int t = threadIdx.x;
  row[t] = fmaxf(fmaf(y1[(size_t)rowid * 128 + t], sc[t], sh[t]), 0.f);
  __syncthreads();
  float acc = bia[t];
  for (int cin = 0; cin < 128; ++cin) acc = fmaf(row[cin], W[(size_t)cin * 128 + t], acc);
  y2[(size_t)rowid * 128 + t] = acc;
}

__global__ __launch_bounds__(256) void s3_kernel(const float* __restrict__ y2,
                                                 const float* __restrict__ sc, const float* __restrict__ sh,
                                                 const float* __restrict__ W, const float* __restrict__ bia,
                                                 float* __restrict__ y3) {
  __shared__ float row[128];
  const int rowid = blockIdx.x;
  const int t = threadIdx.x;
  if (t < 128) row[t] = fmaxf(fmaf(y2[(size_t)rowid * 128 + t], sc[t], sh[t]), 0.f);
  __syncthreads();
  for (int h = 0; h < 2; ++h) {
    const int c = h * 256 + t;
    float acc = bia[c];
    for (int cin = 0; cin < 128; ++cin) acc = fmaf(row[cin], W[(size_t)cin * 512 + c], acc);
    y3[(size_t)rowid * 512 + c] = acc;
  }
}

__global__ __launch_bounds__(256) void s_stats(const float* __restrict__ y, int C, int rows,
                                               const float* __restrict__ g, const float* __restrict__ be,
                                               float* __restrict__ sc, float* __restrict__ sh) {
  const int c = blockIdx.x;
  const int t = threadIdx.x;
  double s = 0.0, q = 0.0;
  for (int r2 = t; r2 < rows; r2 += 256) {
    const double v = (double)y[(size_t)r2 * C + c];
    s += v;
    q += v * v;
  }
  __shared__ double ss[256], qq[256];
  ss[t] = s;
  qq[t] = q;
  __syncthreads();
  for (int st = 128; st > 0; st >>= 1) {
    if (t < st) { ss[t] += ss[t + st]; qq[t] += qq[t + st]; }
    __syncthreads();
  }
  if (t == 0) {
    const double mean = ss[0] / rows;
    double var = qq[0] / rows - mean * mean;
    if (var < 0.0) var = 0.0;
    const float scl = (float)((double)g[c] / sqrt(var + 1e-5));
    sc[c] = scl;
    sh[c] = be[c] - (float)mean * scl;
  }
}

__global__ __launch_bounds__(256) void final_kernel(const float* __restrict__ y3,
                                                    const float* __restrict__ sc, const float* __restrict__ sh,
                                                    float* __restrict__ out) {
  const int gid = blockIdx.x * 256 + threadIdx.x;  // 8192 = 16 batches x 512 ch
  const int b = gid >> 9;
  const int c = gid & 511;
  const float scv = sc[c], shv = sh[c];
  float mx = -3.402823466e+38f;
  for (int m = 0; m < 128; ++m) {
    const float v = fmaxf(fmaf(y3[((size_t)(b * 128 + m)) * 512 + c], scv, shv), 0.f);
    mx = fmaxf(mx, v);
  }
  out[gid] = mx;
  if (gid < 48) out[8192 + gid] = 0.f;  // pos_out zeros
}

extern "C" void kernel_launch(void* const* d_in, const int* in_sizes, int n_in,
                              void* d_out, int out_size, void* d_ws, size_t ws_size,
                              hipStream_t stream) {
  const float* x    = (const float*)d_in[0];
  const float* pos  = (const float*)d_in[1];
  const float* W00  = (const float*)d_in[2];
  const float* b00  = (const float*)d_in[3];
  const float* g00  = (const float*)d_in[4];
  const float* be00 = (const float*)d_in[5];
  const float* W01  = (const float*)d_in[6];
  const float* b01  = (const float*)d_in[7];
  const float* g01  = (const float*)d_in[8];
  const float* be01 = (const float*)d_in[9];
  const float* W02  = (const float*)d_in[10];
  const float* b02  = (const float*)d_in[11];
  const float* g02  = (const float*)d_in[12];
  const float* be02 = (const float*)d_in[13];
  const float* W10  = (const float*)d_in[14];
  const float* b10  = (const float*)d_in[15];
  const float* g10  = (const float*)d_in[16];
  const float* be10 = (const float*)d_in[17];
  const float* W11  = (const float*)d_in[18];
  const float* b11  = (const float*)d_in[19];
  const float* g11  = (const float*)d_in[20];
  const float* be11 = (const float*)d_in[21];
  const float* W12  = (const float*)d_in[22];
  const float* b12  = (const float*)d_in[23];
  const float* g12  = (const float*)d_in[24];
  const float* be12 = (const float*)d_in[25];

  float* w = (float*)d_ws;
  float* sp    = w;                  // 16*128*3          = 6144
  float* gf0   = sp + 6144;          // 16*128*64*6       = 786432
  float* sqsel = gf0 + 786432;       // 16*128*64         = 131072
  float* x1    = sqsel + 131072;     // 16*128*128        = 262144
  float* parts = x1 + 262144;        // 128*2048*2        = 524288
  float* psum  = parts;              // [c][blk]
  float* psq   = parts + 128 * NBLK; // [c][blk]
  float* st    = parts + 524288;     // stats area        = 2048
  float* sc1 = st + 0,    *sh1 = st + 64;
  float* sc2 = st + 128,  *sh2 = st + 192;
  float* sc3 = st + 256,  *sh3 = st + 384;
  float* t1sc = st + 512, *t1sh = st + 640;
  float* t2sc = st + 768, *t2sh = st + 896;
  float* t3sc = st + 1024, *t3sh = st + 1536;
  float* y1s = st + 2048;            // 2048*128 = 262144
  float* y2s = y1s + 262144;         // 2048*128 = 262144
  float* y3s = y2s + 262144;         // 2048*512 = 1048576
  const size_t BASE = 3284992;                   // end of base layout (floats)
  float* y1pre = w + BASE;                       // 2048*4096 = 8388608
  float* y2pre = y1pre + 8388608;                // 8388608
  float* y3pre = y2pre + 8388608;                // 2048*8192 = 16777216
  const size_t NEED = BASE + 8388608ULL * 2 + 16777216ULL;  // 36.8M floats
  const bool big = ws_size >= NEED * sizeof(float);

  fps_kernel<<<BATCH, 1024, 3 * NPTS * sizeof(float), stream>>>(pos, sp);
  knn_kernel<<<BATCH * MS, 256, 0, stream>>>(pos, x, sp, gf0, sqsel);

  const float invN0 = 1.0f / (float)(NBLK * KNB);  // 1/131072
  if (big) {
    l1_kernel<<<NBLK, 256, 0, stream>>>(gf0, W00, b00, psum, psq, y1pre);
    p_stats<<<64, 256, 0, stream>>>(psum, psq, invN0, g00, be00, sc1, sh1);
    l2_kernel<<<NBLK, 256, 0, stream>>>(y1pre, sc1, sh1, W01, b01, psum, psq, y2pre);
    p_stats<<<64, 256, 0, stream>>>(psum, psq, invN0, g01, be01, sc2, sh2);
    l3_kernel<<<NBLK, 256, 0, stream>>>(y2pre, sc2, sh2, W02, b02, psum, psq, y3pre);
    p_stats<<<128, 256, 0, stream>>>(psum, psq, invN0, g02, be02, sc3, sh3);
    l4_kernel<<<NBLK, 128, 0, stream>>>(y3pre, sc3, sh3, sqsel, x1);
  } else {
    chain_kernel<1><<<NBLK, 256, 0, stream>>>(gf0, W00, b00, W01, b01, W02, b02,
                                              sc1, sh1, sc2, sh2, sc3, sh3, sqsel, psum, psq, x1);
    p_stats<<<64, 256, 0, stream>>>(psum, psq, invN0, g00, be00, sc1, sh1);
    chain_kernel<2><<<NBLK, 256, 0, stream>>>(gf0, W00, b00, W01, b01, W02, b02,
                                              sc1, sh1, sc2, sh2, sc3, sh3, sqsel, psum, psq, x1);
    p_stats<<<64, 256, 0, stream>>>(psum, psq, invN0, g01, be01, sc2, sh2);
    chain_kernel<3><<<NBLK, 256, 0, stream>>>(gf0, W00, b00, W01, b01, W02, b02,
                                              sc1, sh1, sc2, sh2, sc3, sh3, sqsel, psum, psq, x1);
    p_stats<<<128, 256, 0, stream>>>(psum, psq, invN0, g02, be02, sc3, sh3);
    chain_kernel<4><<<NBLK, 256, 0, stream>>>(gf0, W00, b00, W01, b01, W02, b02,
                                              sc1, sh1, sc2, sh2, sc3, sh3, sqsel, psum, psq, x1);
  }

  s1_kernel<<<NBLK, 128, 0, stream>>>(sp, x1, W10, b10, y1s);
  s_stats<<<128, 256, 0, stream>>>(y1s, 128, NBLK, g10, be10, t1sc, t1sh);
  s2_kernel<<<NBLK, 128, 0, stream>>>(y1s, t1sc, t1sh, W11, b11, y2s);
  s_stats<<<128, 256, 0, stream>>>(y2s, 128, NBLK, g11, be11, t2sc, t2sh);
  s3_kernel<<<NBLK, 256, 0, stream>>>(y2s, t2sc, t2sh, W12, b12, y3s);
  s_stats<<<512, 256, 0, stream>>>(y3s, 512, NBLK, g12, be12, t3sc, t3sh);
  final_kernel<<<32, 256, 0, stream>>>(y3s, t3sc, t3sh, (float*)d_out);
}

// Round 11
// 440.483 us; speedup vs baseline: 1.1795x; 1.0061x over previous
//
#include <hip/hip_runtime.h>
#include <cstdint>
#include <cstddef>

#define NPTS 8192
#define BATCH 16
#define MS 128
#define KNB 64
#define NBLK (BATCH * MS)   // 2048

// ---------------- DPP wave reductions (VALU-speed, no LDS crossbar) ----------
__device__ __forceinline__ float dpp_wave_max_f32(float v) {
  v = fmaxf(v, __int_as_float(__builtin_amdgcn_update_dpp((int)0xff800000, __float_as_int(v), 0x111, 0xf, 0xf, false)));
  v = fmaxf(v, __int_as_float(__builtin_amdgcn_update_dpp((int)0xff800000, __float_as_int(v), 0x112, 0xf, 0xf, false)));
  v = fmaxf(v, __int_as_float(__builtin_amdgcn_update_dpp((int)0xff800000, __float_as_int(v), 0x114, 0xf, 0xf, false)));
  v = fmaxf(v, __int_as_float(__builtin_amdgcn_update_dpp((int)0xff800000, __float_as_int(v), 0x118, 0xf, 0xf, false)));
  v = fmaxf(v, __int_as_float(__builtin_amdgcn_update_dpp((int)0xff800000, __float_as_int(v), 0x142, 0xa, 0xf, false)));
  v = fmaxf(v, __int_as_float(__builtin_amdgcn_update_dpp((int)0xff800000, __float_as_int(v), 0x143, 0xc, 0xf, false)));
  return v;  // lane 63
}

__device__ __forceinline__ float dpp_wave_min_f32(float v) {
  v = fminf(v, __int_as_float(__builtin_amdgcn_update_dpp(0x7f800000, __float_as_int(v), 0x111, 0xf, 0xf, false)));
  v = fminf(v, __int_as_float(__builtin_amdgcn_update_dpp(0x7f800000, __float_as_int(v), 0x112, 0xf, 0xf, false)));
  v = fminf(v, __int_as_float(__builtin_amdgcn_update_dpp(0x7f800000, __float_as_int(v), 0x114, 0xf, 0xf, false)));
  v = fminf(v, __int_as_float(__builtin_amdgcn_update_dpp(0x7f800000, __float_as_int(v), 0x118, 0xf, 0xf, false)));
  v = fminf(v, __int_as_float(__builtin_amdgcn_update_dpp(0x7f800000, __float_as_int(v), 0x142, 0xa, 0xf, false)));
  v = fminf(v, __int_as_float(__builtin_amdgcn_update_dpp(0x7f800000, __float_as_int(v), 0x143, 0xc, 0xf, false)));
  return v;  // lane 63
}

__device__ __forceinline__ unsigned dpp_wave_min_u32(unsigned v) {
  unsigned o;
  o = (unsigned)__builtin_amdgcn_update_dpp((int)0xffffffffu, (int)v, 0x111, 0xf, 0xf, false); v = (o < v) ? o : v;
  o = (unsigned)__builtin_amdgcn_update_dpp((int)0xffffffffu, (int)v, 0x112, 0xf, 0xf, false); v = (o < v) ? o : v;
  o = (unsigned)__builtin_amdgcn_update_dpp((int)0xffffffffu, (int)v, 0x114, 0xf, 0xf, false); v = (o < v) ? o : v;
  o = (unsigned)__builtin_amdgcn_update_dpp((int)0xffffffffu, (int)v, 0x118, 0xf, 0xf, false); v = (o < v) ? o : v;
  o = (unsigned)__builtin_amdgcn_update_dpp((int)0xffffffffu, (int)v, 0x142, 0xa, 0xf, false); v = (o < v) ? o : v;
  o = (unsigned)__builtin_amdgcn_update_dpp((int)0xffffffffu, (int)v, 0x143, 0xc, 0xf, false); v = (o < v) ? o : v;
  return v;  // lane 63
}

__device__ __forceinline__ float dpp_row_max_f32(float v) {  // lane 15 of each row
  v = fmaxf(v, __int_as_float(__builtin_amdgcn_update_dpp((int)0xff800000, __float_as_int(v), 0x111, 0xf, 0xf, false)));
  v = fmaxf(v, __int_as_float(__builtin_amdgcn_update_dpp((int)0xff800000, __float_as_int(v), 0x112, 0xf, 0xf, false)));
  v = fmaxf(v, __int_as_float(__builtin_amdgcn_update_dpp((int)0xff800000, __float_as_int(v), 0x114, 0xf, 0xf, false)));
  v = fmaxf(v, __int_as_float(__builtin_amdgcn_update_dpp((int)0xff800000, __float_as_int(v), 0x118, 0xf, 0xf, false)));
  return v;
}

__device__ __forceinline__ unsigned dpp_row_min_u32(unsigned v) {  // lane 15 of each row
  unsigned o;
  o = (unsigned)__builtin_amdgcn_update_dpp((int)0xffffffffu, (int)v, 0x111, 0xf, 0xf, false); v = (o < v) ? o : v;
  o = (unsigned)__builtin_amdgcn_update_dpp((int)0xffffffffu, (int)v, 0x112, 0xf, 0xf, false); v = (o < v) ? o : v;
  o = (unsigned)__builtin_amdgcn_update_dpp((int)0xffffffffu, (int)v, 0x114, 0xf, 0xf, false); v = (o < v) ? o : v;
  o = (unsigned)__builtin_amdgcn_update_dpp((int)0xffffffffu, (int)v, 0x118, 0xf, 0xf, false); v = (o < v) ? o : v;
  return v;
}

__device__ __forceinline__ float dpp_quad_min_f32(float v) {  // lane 3
  v = fminf(v, __int_as_float(__builtin_amdgcn_update_dpp(0x7f800000, __float_as_int(v), 0x111, 0xf, 0xf, false)));
  v = fminf(v, __int_as_float(__builtin_amdgcn_update_dpp(0x7f800000, __float_as_int(v), 0x112, 0xf, 0xf, false)));
  return v;
}

__device__ __forceinline__ unsigned dpp_quad_min_u32(unsigned v) {  // lane 3
  unsigned o;
  o = (unsigned)__builtin_amdgcn_update_dpp((int)0xffffffffu, (int)v, 0x111, 0xf, 0xf, false); v = (o < v) ? o : v;
  o = (unsigned)__builtin_amdgcn_update_dpp((int)0xffffffffu, (int)v, 0x112, 0xf, 0xf, false); v = (o < v) ? o : v;
  return v;
}

// ---------------------------------------------------------------- FPS
// Round-9 analysis: the loop was LDS-ISSUE-bound -- 24 ds_read_b32/thread/iter
// = 384 wave-ops x 5.8cyc ~ 2230 cyc/iter on the LDS pipe (VALU ~960 overlaps).
// Fix: float4 point layout -> ONE ds_read_b128 per point (8/thread/iter,
// 128 wave-ops x ~12cyc ~ 1540 cyc/iter; 85 B/cyc vs b32's 44 B/cyc).
// Arithmetic order (contract off) and the DPP reduce are unchanged =>
// identical selections.
#define FPS_STEP(J)                                                        \
  {                                                                        \
    const float4 p = pts4[J * 1024 + t];                                   \
    const float dx = p.x - lx;                                             \
    const float dy = p.y - ly;                                             \
    const float dz = p.z - lz;                                             \
    const float d = dx * dx + dy * dy + dz * dz;                           \
    md##J = fminf(md##J, d);                                               \
  }

#define FPS_RESCAN(J)                                                      \
  if (md##J == wv) best = (unsigned)(J * 1024 + t);

__global__ __launch_bounds__(1024, 4) void fps_kernel(const float* __restrict__ pos,
                                                      float* __restrict__ sp) {
#pragma clang fp contract(off)
  extern __shared__ float4 pts4[];  // 8192 * 16B = 128KB dynamic
  __shared__ float wval[2][16];
  __shared__ unsigned widx[2][16];
  const int b = blockIdx.x;
  const float* P = pos + (size_t)b * NPTS * 3;
  const int t = threadIdx.x;
  const int wave = t >> 6;
  const int lane = t & 63;
  float md0 = 1e10f, md1 = 1e10f, md2 = 1e10f, md3 = 1e10f;
  float md4 = 1e10f, md5 = 1e10f, md6 = 1e10f, md7 = 1e10f;
  for (int i = t; i < NPTS; i += 1024)
    pts4[i] = make_float4(P[i * 3 + 0], P[i * 3 + 1], P[i * 3 + 2], 0.f);
  float lx = P[0], ly = P[1], lz = P[2];
  __syncthreads();
  for (int it = 0; it < MS; ++it) {
    if (t == 0) {
      sp[((size_t)b * MS + it) * 3 + 0] = lx;
      sp[((size_t)b * MS + it) * 3 + 1] = ly;
      sp[((size_t)b * MS + it) * 3 + 2] = lz;
    }
    FPS_STEP(0) FPS_STEP(1) FPS_STEP(2) FPS_STEP(3)
    FPS_STEP(4) FPS_STEP(5) FPS_STEP(6) FPS_STEP(7)
    const float m01 = fmaxf(md0, md1), m23 = fmaxf(md2, md3);
    const float m45 = fmaxf(md4, md5), m67 = fmaxf(md6, md7);
    const float bv = fmaxf(fmaxf(m01, m23), fmaxf(m45, m67));
    const float wv = __int_as_float(
        __builtin_amdgcn_readlane(__float_as_int(dpp_wave_max_f32(bv)), 63));
    unsigned best = 0xffffffffu;
    if (bv == wv) {
      FPS_RESCAN(7) FPS_RESCAN(6) FPS_RESCAN(5) FPS_RESCAN(4)
      FPS_RESCAN(3) FPS_RESCAN(2) FPS_RESCAN(1) FPS_RESCAN(0)
    }
    const unsigned wi =
        (unsigned)__builtin_amdgcn_readlane((int)dpp_wave_min_u32(best), 63);
    const int par = it & 1;
    if (lane == 0) { wval[par][wave] = wv; widx[par][wave] = wi; }
    __syncthreads();
    const float a = wval[par][lane & 15];
    const float M = __int_as_float(
        __builtin_amdgcn_readlane(__float_as_int(dpp_row_max_f32(a)), 15));
    const unsigned c2 = (a == M) ? widx[par][lane & 15] : 0xffffffffu;
    const unsigned idx =
        (unsigned)__builtin_amdgcn_readlane((int)dpp_row_min_u32(c2), 15);
    const float4 c = pts4[idx];  // same addr across lanes -> broadcast
    lx = c.x; ly = c.y; lz = c.z;
  }
}

// ---------------------------------------------------------------- kNN top-64
__global__ __launch_bounds__(256) void knn_kernel(const float* __restrict__ pos,
                                                  const float* __restrict__ xf,
                                                  const float* __restrict__ sp,
                                                  float* __restrict__ gf0,
                                                  float* __restrict__ sqsel) {
#pragma clang fp contract(off)
  __shared__ float sqv[NPTS];
  __shared__ float wval[2][4];
  __shared__ unsigned widx[2][4];
  __shared__ int sel_i[KNB];
  __shared__ float sel_v[KNB];
  const int bm = blockIdx.x;
  const int b = bm >> 7;
  const float* P = pos + (size_t)b * NPTS * 3;
  const float sx = sp[bm * 3 + 0], sy = sp[bm * 3 + 1], sz = sp[bm * 3 + 2];
  const float nsp = sx * sx + sy * sy + sz * sz;
  const int t = threadIdx.x;
  const int wave = t >> 6;
  const int lane = t & 63;
  for (int j = 0; j < 32; ++j) {
    const int i = j * 256 + t;
    const float qx = P[i * 3 + 0], qy = P[i * 3 + 1], qz = P[i * 3 + 2];
    const float npos = qx * qx + qy * qy + qz * qz;
    const float dt = sx * qx + sy * qy + sz * qz;
    float sq = (nsp + npos) - 2.0f * dt;  // matches ||a||^2+||b||^2-2ab order
    sq = fmaxf(sq, 0.0f);
    sqv[i] = sq;
  }
  __syncthreads();
  float cv;
  unsigned ci;
  {
    unsigned long long k0 = ~0ULL;
    for (int j = 0; j < 32; ++j) {
      const int i = j * 256 + t;
      const unsigned long long key =
          ((unsigned long long)__float_as_uint(sqv[i]) << 32) | (unsigned)i;
      if (key < k0) k0 = key;
    }
    cv = __uint_as_float((unsigned)(k0 >> 32));
    ci = (unsigned)k0;
  }
  for (int round = 0; round < KNB; ++round) {
    const float wv = __int_as_float(
        __builtin_amdgcn_readlane(__float_as_int(dpp_wave_min_f32(cv)), 63));
    const unsigned sel = (cv == wv) ? ci : 0xffffffffu;
    const unsigned wi =
        (unsigned)__builtin_amdgcn_readlane((int)dpp_wave_min_u32(sel), 63);
    const int par = round & 1;
    if (lane == 0) { wval[par][wave] = wv; widx[par][wave] = wi; }
    __syncthreads();
    const float a = wval[par][lane & 3];
    const float M = __int_as_float(
        __builtin_amdgcn_readlane(__float_as_int(dpp_quad_min_f32(a)), 3));
    const unsigned c2 = (a == M) ? widx[par][lane & 3] : 0xffffffffu;
    const unsigned idx =
        (unsigned)__builtin_amdgcn_readlane((int)dpp_quad_min_u32(c2), 3);
    const int col = (int)(idx & 255u);
    if (t == col) {
      sel_i[round] = (int)idx;
      sel_v[round] = M;
      sqv[idx] = __uint_as_float(0x7f800000u);  // consumed (visible next round)
    }
    if (wave == (col >> 6)) {
      float v = __uint_as_float(0x7f800000u);
      unsigned ii = 0xffffffffu;
      if (lane < 32) {
        const int i = lane * 256 + col;
        v = sqv[i];
        if (i == (int)idx) v = __uint_as_float(0x7f800000u);
        ii = (unsigned)i;
      }
      const float mv = __int_as_float(
          __builtin_amdgcn_readlane(__float_as_int(dpp_wave_min_f32(v)), 63));
      const unsigned s2 = (v == mv) ? ii : 0xffffffffu;
      const unsigned mi =
          (unsigned)__builtin_amdgcn_readlane((int)dpp_wave_min_u32(s2), 63);
      if (t == col) { cv = mv; ci = mi; }
    }
  }
  __syncthreads();
  if (t < KNB) {
    const int i = sel_i[t];
    const float* X = xf + (size_t)b * NPTS * 3;
    const size_t base = ((size_t)bm * KNB + t) * 6;
    gf0[base + 0] = P[i * 3 + 0] - sx;
    gf0[base + 1] = P[i * 3 + 1] - sy;
    gf0[base + 2] = P[i * 3 + 2] - sz;
    gf0[base + 3] = X[i * 3 + 0];
    gf0[base + 4] = X[i * 3 + 1];
    gf0[base + 5] = X[i * 3 + 2];
    sqsel[(size_t)bm * KNB + t] = sel_v[t];
  }
}

// ================================================================ chain
// Single-compute stack with pre-BN activation caching + register-tiled GEMMs.

__global__ __launch_bounds__(256) void l1_kernel(
    const float* __restrict__ gf0, const float* __restrict__ W0,
    const float* __restrict__ B0,
    float* __restrict__ psum, float* __restrict__ psq,
    float* __restrict__ y1pre) {
  __shared__ float in6[64 * 8];
  __shared__ float wbuf[384];
  __shared__ float out[64 * 65];
  const int blk = blockIdx.x;
  const int t = threadIdx.x;
  const float* G = gf0 + (size_t)blk * 384;
  for (int i = t; i < 384; i += 256) in6[(i / 6) * 8 + (i % 6)] = G[i];
  for (int i = t; i < 384; i += 256) wbuf[i] = W0[i];
  __syncthreads();
  const int r = t >> 2;
  const int c0 = (t & 3) * 16;
  float acc[16];
#pragma unroll
  for (int j = 0; j < 16; ++j) acc[j] = B0[c0 + j];
  for (int cin = 0; cin < 6; ++cin) {
    const float a = in6[r * 8 + cin];
#pragma unroll
    for (int j = 0; j < 16; ++j) acc[j] = fmaf(a, wbuf[cin * 64 + c0 + j], acc[j]);
  }
#pragma unroll
  for (int j = 0; j < 16; ++j) out[r * 65 + c0 + j] = acc[j];
  __syncthreads();
  if (t < 64) {
    float s = 0.f, q = 0.f;
    for (int r2 = 0; r2 < 64; ++r2) { const float v = out[r2 * 65 + t]; s += v; q += v * v; }
    psum[(size_t)t * NBLK + blk] = s;
    psq[(size_t)t * NBLK + blk] = q;
  }
  float* Y = y1pre + (size_t)blk * 4096;
  for (int i = t; i < 4096; i += 256) Y[i] = out[(i >> 6) * 65 + (i & 63)];
}

__global__ __launch_bounds__(256) void l2_kernel(
    const float* __restrict__ ypre, const float* __restrict__ sc,
    const float* __restrict__ sh, const float* __restrict__ W1,
    const float* __restrict__ B1,
    float* __restrict__ psum, float* __restrict__ psq,
    float* __restrict__ yout) {
  __shared__ float As[64 * 68];
  __shared__ float Bs[64 * 64];
  __shared__ float out[64 * 68];
  const int blk = blockIdx.x;
  const int t = threadIdx.x;
  const float* Y = ypre + (size_t)blk * 4096;
  for (int i = t; i < 4096; i += 256) {
    const int c = i & 63;
    As[(i >> 6) * 68 + c] = fmaxf(fmaf(Y[i], sc[c], sh[c]), 0.f);
  }
  for (int i = t; i < 4096; i += 256) Bs[i] = W1[i];
  __syncthreads();
  const int tr = t >> 4;
  const int tc4 = (t & 15) * 4;
  float acc[4][4];
#pragma unroll
  for (int s = 0; s < 4; ++s)
#pragma unroll
    for (int j = 0; j < 4; ++j) acc[s][j] = B1[tc4 + j];
  for (int k0 = 0; k0 < 64; k0 += 4) {
    float4 av[4];
#pragma unroll
    for (int s = 0; s < 4; ++s)
      av[s] = *reinterpret_cast<const float4*>(&As[(tr + 16 * s) * 68 + k0]);
#pragma unroll
    for (int kk = 0; kk < 4; ++kk) {
      const float4 bv = *reinterpret_cast<const float4*>(&Bs[(k0 + kk) * 64 + tc4]);
#pragma unroll
      for (int s = 0; s < 4; ++s) {
        const float a = (kk == 0) ? av[s].x : (kk == 1) ? av[s].y
                       : (kk == 2) ? av[s].z : av[s].w;
        acc[s][0] = fmaf(a, bv.x, acc[s][0]);
        acc[s][1] = fmaf(a, bv.y, acc[s][1]);
        acc[s][2] = fmaf(a, bv.z, acc[s][2]);
        acc[s][3] = fmaf(a, bv.w, acc[s][3]);
      }
    }
  }
#pragma unroll
  for (int s = 0; s < 4; ++s) {
    float4 o;
    o.x = acc[s][0]; o.y = acc[s][1]; o.z = acc[s][2]; o.w = acc[s][3];
    *reinterpret_cast<float4*>(&out[(tr + 16 * s) * 68 + tc4]) = o;
  }
  __syncthreads();
  if (t < 64) {
    float s = 0.f, q = 0.f;
    for (int r2 = 0; r2 < 64; ++r2) { const float v = out[r2 * 68 + t]; s += v; q += v * v; }
    psum[(size_t)t * NBLK + blk] = s;
    psq[(size_t)t * NBLK + blk] = q;
  }
  float* O = yout + (size_t)blk * 4096;
  for (int i = t; i < 4096; i += 256) O[i] = out[(i >> 6) * 68 + (i & 63)];
}

__global__ __launch_bounds__(256) void l3_kernel(
    const float* __restrict__ ypre, const float* __restrict__ sc,
    const float* __restrict__ sh, const float* __restrict__ W2,
    const float* __restrict__ B2,
    float* __restrict__ psum, float* __restrict__ psq,
    float* __restrict__ yout) {
  __shared__ float As[64 * 68];
  __shared__ float Bs[64 * 64];
  __shared__ float out[64 * 68];
  const int blk = blockIdx.x;
  const int t = threadIdx.x;
  const float* Y = ypre + (size_t)blk * 4096;
  for (int i = t; i < 4096; i += 256) {
    const int c = i & 63;
    As[(i >> 6) * 68 + c] = fmaxf(fmaf(Y[i], sc[c], sh[c]), 0.f);
  }
  const int tr = t >> 4;
  const int tc4 = (t & 15) * 4;
  for (int hc = 0; hc < 2; ++hc) {
    __syncthreads();
    for (int i = t; i < 4096; i += 256)
      Bs[i] = W2[(i >> 6) * 128 + hc * 64 + (i & 63)];
    __syncthreads();
    float acc[4][4];
#pragma unroll
    for (int s = 0; s < 4; ++s)
#pragma unroll
      for (int j = 0; j < 4; ++j) acc[s][j] = B2[hc * 64 + tc4 + j];
    for (int k0 = 0; k0 < 64; k0 += 4) {
      float4 av[4];
#pragma unroll
      for (int s = 0; s < 4; ++s)
        av[s] = *reinterpret_cast<const float4*>(&As[(tr + 16 * s) * 68 + k0]);
#pragma unroll
      for (int kk = 0; kk < 4; ++kk) {
        const float4 bv = *reinterpret_cast<const float4*>(&Bs[(k0 + kk) * 64 + tc4]);
#pragma unroll
        for (int s = 0; s < 4; ++s) {
          const float a = (kk == 0) ? av[s].x : (kk == 1) ? av[s].y
                         : (kk == 2) ? av[s].z : av[s].w;
          acc[s][0] = fmaf(a, bv.x, acc[s][0]);
          acc[s][1] = fmaf(a, bv.y, acc[s][1]);
          acc[s][2] = fmaf(a, bv.z, acc[s][2]);
          acc[s][3] = fmaf(a, bv.w, acc[s][3]);
        }
      }
    }
#pragma unroll
    for (int s = 0; s < 4; ++s) {
      float4 o;
      o.x = acc[s][0]; o.y = acc[s][1]; o.z = acc[s][2]; o.w = acc[s][3];
      *reinterpret_cast<float4*>(&out[(tr + 16 * s) * 68 + tc4]) = o;
    }
    __syncthreads();
    if (t < 64) {
      float s = 0.f, q = 0.f;
      for (int r2 = 0; r2 < 64; ++r2) { const float v = out[r2 * 68 + t]; s += v; q += v * v; }
      psum[(size_t)(hc * 64 + t) * NBLK + blk] = s;
      psq[(size_t)(hc * 64 + t) * NBLK + blk] = q;
    }
    float* O = yout + (size_t)blk * 8192;
    for (int i = t; i < 4096; i += 256)
      O[(i >> 6) * 128 + hc * 64 + (i & 63)] = out[(i >> 6) * 68 + (i & 63)];
  }
}

__global__ __launch_bounds__(128) void l4_kernel(
    const float* __restrict__ y3pre, const float* __restrict__ sc3,
    const float* __restrict__ sh3, const float* __restrict__ sqsel,
    float* __restrict__ x1) {
  __shared__ float sqs[64];
  const int blk = blockIdx.x;
  const int t = threadIdx.x;
  if (t < 64) sqs[t] = sqsel[(size_t)blk * 64 + t];
  __syncthreads();
  const float scv = sc3[t], shv = sh3[t];
  const float* Y = y3pre + (size_t)blk * 8192;
  float mx = -1e8f;
  for (int r = 0; r < 64; ++r) {
    const float act = fmaxf(fmaf(Y[r * 128 + t], scv, shv), 0.f);
    const float v = (sqs[r] <= 0.16f) ? act : -1e8f;
    mx = fmaxf(mx, v);
  }
  x1[(size_t)blk * 128 + t] = mx;
}

// ---------------- OLD recompute chain (fallback when ws too small) ----------
template <int MODE>
__global__ __launch_bounds__(256) void chain_kernel(
    const float* __restrict__ gf0,
    const float* __restrict__ W0, const float* __restrict__ B0,
    const float* __restrict__ W1, const float* __restrict__ B1,
    const float* __restrict__ W2, const float* __restrict__ B2,
    const float* __restrict__ sc1, const float* __restrict__ sh1,
    const float* __restrict__ sc2, const float* __restrict__ sh2,
    const float* __restrict__ sc3, const float* __restrict__ sh3,
    const float* __restrict__ sqsel,
    float* __restrict__ psum, float* __restrict__ psq, float* __restrict__ x1) {
  __shared__ float tA[64 * 65];
  __shared__ float tB[64 * 65];
  __shared__ float wbuf[64 * 64];
  __shared__ float in6[64 * 8];
  __shared__ float sqs[64];
  const int blk = blockIdx.x;
  const int t = threadIdx.x;
  {
    const float* G = gf0 + (size_t)blk * 64 * 6;
    for (int i = t; i < 384; i += 256) in6[(i / 6) * 8 + (i % 6)] = G[i];
    for (int i = t; i < 384; i += 256) wbuf[i] = W0[i];
    if (MODE == 4 && t < 64) sqs[t] = sqsel[(size_t)blk * 64 + t];
  }
  __syncthreads();
  const int r = t >> 2;
  const int c0 = (t & 3) * 16;
  float acc[16];
#pragma unroll
  for (int j = 0; j < 16; ++j) acc[j] = B0[c0 + j];
  for (int cin = 0; cin < 6; ++cin) {
    const float a = in6[r * 8 + cin];
#pragma unroll
    for (int j = 0; j < 16; ++j) acc[j] = fmaf(a, wbuf[cin * 64 + c0 + j], acc[j]);
  }
  if (MODE == 1) {
#pragma unroll
    for (int j = 0; j < 16; ++j) tA[r * 65 + c0 + j] = acc[j];
    __syncthreads();
    if (t < 64) {
      float s = 0.f, q = 0.f;
      for (int r2 = 0; r2 < 64; ++r2) { const float v = tA[r2 * 65 + t]; s += v; q += v * v; }
      psum[(size_t)t * NBLK + blk] = s;
      psq[(size_t)t * NBLK + blk] = q;
    }
    return;
  }
#pragma unroll
  for (int j = 0; j < 16; ++j) {
    const int c = c0 + j;
    tA[r * 65 + c] = fmaxf(fmaf(acc[j], sc1[c], sh1[c]), 0.f);
  }
  __syncthreads();
  for (int i = t; i < 4096; i += 256) wbuf[i] = W1[i];
  __syncthreads();
#pragma unroll
  for (int j = 0; j < 16; ++j) acc[j] = B1[c0 + j];
  for (int cin = 0; cin < 64; ++cin) {
    const float a = tA[r * 65 + cin];
    const float4* w4 = reinterpret_cast<const float4*>(&wbuf[cin * 64 + c0]);
#pragma unroll
    for (int k = 0; k < 4; ++k) {
      const float4 w = w4[k];
      acc[k * 4 + 0] = fmaf(a, w.x, acc[k * 4 + 0]);
      acc[k * 4 + 1] = fmaf(a, w.y, acc[k * 4 + 1]);
      acc[k * 4 + 2] = fmaf(a, w.z, acc[k * 4 + 2]);
      acc[k * 4 + 3] = fmaf(a, w.w, acc[k * 4 + 3]);
    }
  }
  if (MODE == 2) {
#pragma unroll
    for (int j = 0; j < 16; ++j) tB[r * 65 + c0 + j] = acc[j];
    __syncthreads();
    if (t < 64) {
      float s = 0.f, q = 0.f;
      for (int r2 = 0; r2 < 64; ++r2) { const float v = tB[r2 * 65 + t]; s += v; q += v * v; }
      psum[(size_t)t * NBLK + blk] = s;
      psq[(size_t)t * NBLK + blk] = q;
    }
    return;
  }
#pragma unroll
  for (int j = 0; j < 16; ++j) {
    const int c = c0 + j;
    tB[r * 65 + c] = fmaxf(fmaf(acc[j], sc2[c], sh2[c]), 0.f);
  }
  for (int hc = 0; hc < 2; ++hc) {
    __syncthreads();
    for (int i = t; i < 4096; i += 256) {
      const int cin = i >> 6, cc = i & 63;
      wbuf[i] = W2[cin * 128 + hc * 64 + cc];
    }
    __syncthreads();
    float st_s = 0.f, st_q = 0.f, mx = -1e8f;
    for (int rh = 0; rh < 2; ++rh) {
      const int rr = rh * 32 + (t >> 3);
      const int cc0 = (t & 7) * 8;
      float a3[8];
#pragma unroll
      for (int j = 0; j < 8; ++j) a3[j] = B2[hc * 64 + cc0 + j];
      for (int cin = 0; cin < 64; ++cin) {
        const float a = tB[rr * 65 + cin];
        const float4* w4 = reinterpret_cast<const float4*>(&wbuf[cin * 64 + cc0]);
#pragma unroll
        for (int k = 0; k < 2; ++k) {
          const float4 w = w4[k];
          a3[k * 4 + 0] = fmaf(a, w.x, a3[k * 4 + 0]);
          a3[k * 4 + 1] = fmaf(a, w.y, a3[k * 4 + 1]);
          a3[k * 4 + 2] = fmaf(a, w.z, a3[k * 4 + 2]);
          a3[k * 4 + 3] = fmaf(a, w.w, a3[k * 4 + 3]);
        }
      }
      __syncthreads();
#pragma unroll
      for (int j = 0; j < 8; ++j) tA[(t >> 3) * 65 + cc0 + j] = a3[j];
      __syncthreads();
      if (t < 64) {
        if (MODE == 3) {
          for (int q2 = 0; q2 < 32; ++q2) { const float v = tA[q2 * 65 + t]; st_s += v; st_q += v * v; }
        } else {
          const float scv = sc3[hc * 64 + t], shv = sh3[hc * 64 + t];
          for (int q2 = 0; q2 < 32; ++q2) {
            const int kidx = rh * 32 + q2;
            const float y = tA[q2 * 65 + t];
            const float act = fmaxf(fmaf(y, scv, shv), 0.f);
            const float v = (sqs[kidx] <= 0.16f) ? act : -1e8f;
            mx = fmaxf(mx, v);
          }
        }
      }
      __syncthreads();
    }
    if (t < 64) {
      if (MODE == 3) {
        psum[(size_t)(hc * 64 + t) * NBLK + blk] = st_s;
        psq[(size_t)(hc * 64 + t) * NBLK + blk] = st_q;
      } else if (MODE == 4) {
        x1[(size_t)blk * 128 + hc * 64 + t] = mx;
      }
    }
  }
}

// Parallel deterministic stats reduce: one block per channel, f64 LDS tree.
__global__ __launch_bounds__(256) void p_stats(const float* __restrict__ psum,
                                               const float* __restrict__ psq,
                                               float invN,
                                               const float* __restrict__ g,
                                               const float* __restrict__ be,
                                               float* __restrict__ sc,
                                               float* __restrict__ sh) {
  const int c = blockIdx.x;
  const int t = threadIdx.x;
  double s = 0.0, q = 0.0;
  for (int k = t; k < NBLK; k += 256) {
    s += (double)psum[(size_t)c * NBLK + k];
    q += (double)psq[(size_t)c * NBLK + k];
  }
  __shared__ double ss[256], qq[256];
  ss[t] = s;
  qq[t] = q;
  __syncthreads();
  for (int st = 128; st > 0; st >>= 1) {
    if (t < st) { ss[t] += ss[t + st]; qq[t] += qq[t + st]; }
    __syncthreads();
  }
  if (t == 0) {
    const double mean = ss[0] * (double)invN;
    double var = qq[0] * (double)invN - mean * mean;
    if (var < 0.0) var = 0.0;
    const float scl = (float)((double)g[c] / sqrt(var + 1e-5));
    sc[c] = scl;
    sh[c] = be[c] - (float)mean * scl;
  }
}

// ---------------------------------------------------------------- stage 1
__global__ __launch_bounds__(128) void s1_kernel(const float* __restrict__ sp,
                                                 const float* __restrict__ x1,
                                                 const float* __restrict__ W,
                                                 const float* __restrict__ bia,
                                                 float* __restrict__ y1) {
  __shared__ float row[132];
  const int rowid = blockIdx.x;
  const int t = threadIdx.x;
  if (t < 3) row[t] = sp[(size_t)rowid * 3 + t];
  row[3 + t] = x1[(size_t)rowid * 128 + t];
  __syncthreads();
  float acc = bia[t];
  for (int cin = 0; cin < 131; ++cin) acc = fmaf(row[cin], W[(size_t)cin * 128 + t], acc);
  y1[(size_t)rowid * 128 + t] = acc;
}

__global__ __launch_bounds__(128) void s2_kernel(const float* __restrict__ y1,
                                                 const float* __restrict__ sc, const float* __restrict__ sh,
                                                 const float* __restrict__ W, const float* __restrict__ bia,
                                                 float* __restrict__ y2) {
  __shared__ float row[128];
  const int rowid = blockIdx.x;
  const int t = threadIdx.x;
  row[t] = fmaxf(fmaf(y1[(size_t)rowid * 128 + t], sc[t], sh[t]), 0.f);
  __syncthreads();
  float acc = bia[t];
  for (int cin = 0; cin < 128; ++cin) acc = fmaf(row[cin], W[(size_t)cin * 128 + t], acc);
  y2[(size_t)rowid * 128 + t] = acc;
}

__global__ __launch_bounds__(256) void s3_kernel(const float* __restrict__ y2,
                                                 const float* __restrict__ sc, const float* __restrict__ sh,
                                                 const float* __restrict__ W, const float* __restrict__ bia,
                                                 float* __restrict__ y3) {
  __shared__ float row[128];
  const int rowid = blockIdx.x;
  const int t = threadIdx.x;
  if (t < 128) row[t] = fmaxf(fmaf(y2[(size_t)rowid * 128 + t], sc[t], sh[t]), 0.f);
  __syncthreads();
  for (int h = 0; h < 2; ++h) {
    const int c = h * 256 + t;
    float acc = bia[c];
    for (int cin = 0; cin < 128; ++cin) acc = fmaf(row[cin], W[(size_t)cin * 512 + c], acc);
    y3[(size_t)rowid * 512 + c] = acc;
  }
}

__global__ __launch_bounds__(256) void s_stats(const float* __restrict__ y, int C, int rows,
                                               const float* __restrict__ g, const float* __restrict__ be,
                                               float* __restrict__ sc, float* __restrict__ sh) {
  const int c = blockIdx.x;
  const int t = threadIdx.x;
  double s = 0.0, q = 0.0;
  for (int r2 = t; r2 < rows; r2 += 256) {
    const double v = (double)y[(size_t)r2 * C + c];
    s += v;
    q += v * v;
  }
  __shared__ double ss[256], qq[256];
  ss[t] = s;
  qq[t] = q;
  __syncthreads();
  for (int st = 128; st > 0; st >>= 1) {
    if (t < st) { ss[t] += ss[t + st]; qq[t] += qq[t + st]; }
    __syncthreads();
  }
  if (t == 0) {
    const double mean = ss[0] / rows;
    double var = qq[0] / rows - mean * mean;
    if (var < 0.0) var = 0.0;
    const float scl = (float)((double)g[c] / sqrt(var + 1e-5));
    sc[c] = scl;
    sh[c] = be[c] - (float)mean * scl;
  }
}

__global__ __launch_bounds__(256) void final_kernel(const float* __restrict__ y3,
                                                    const float* __restrict__ sc, const float* __restrict__ sh,
                                                    float* __restrict__ out) {
  const int gid = blockIdx.x * 256 + threadIdx.x;  // 8192 = 16 batches x 512 ch
  const int b = gid >> 9;
  const int c = gid & 511;
  const float scv = sc[c], shv = sh[c];
  float mx = -3.402823466e+38f;
  for (int m = 0; m < 128; ++m) {
    const float v = fmaxf(fmaf(y3[((size_t)(b * 128 + m)) * 512 + c], scv, shv), 0.f);
    mx = fmaxf(mx, v);
  }
  out[gid] = mx;
  if (gid < 48) out[8192 + gid] = 0.f;  // pos_out zeros
}

extern "C" void kernel_launch(void* const* d_in, const int* in_sizes, int n_in,
                              void* d_out, int out_size, void* d_ws, size_t ws_size,
                              hipStream_t stream) {
  const float* x    = (const float*)d_in[0];
  const float* pos  = (const float*)d_in[1];
  const float* W00  = (const float*)d_in[2];
  const float* b00  = (const float*)d_in[3];
  const float* g00  = (const float*)d_in[4];
  const float* be00 = (const float*)d_in[5];
  const float* W01  = (const float*)d_in[6];
  const float* b01  = (const float*)d_in[7];
  const float* g01  = (const float*)d_in[8];
  const float* be01 = (const float*)d_in[9];
  const float* W02  = (const float*)d_in[10];
  const float* b02  = (const float*)d_in[11];
  const float* g02  = (const float*)d_in[12];
  const float* be02 = (const float*)d_in[13];
  const float* W10  = (const float*)d_in[14];
  const float* b10  = (const float*)d_in[15];
  const float* g10  = (const float*)d_in[16];
  const float* be10 = (const float*)d_in[17];
  const float* W11  = (const float*)d_in[18];
  const float* b11  = (const float*)d_in[19];
  const float* g11  = (const float*)d_in[20];
  const float* be11 = (const float*)d_in[21];
  const float* W12  = (const float*)d_in[22];
  const float* b12  = (const float*)d_in[23];
  const float* g12  = (const float*)d_in[24];
  const float* be12 = (const float*)d_in[25];

  float* w = (float*)d_ws;
  float* sp    = w;                  // 16*128*3          = 6144
  float* gf0   = sp + 6144;          // 16*128*64*6       = 786432
  float* sqsel = gf0 + 786432;       // 16*128*64         = 131072
  float* x1    = sqsel + 131072;     // 16*128*128        = 262144
  float* parts = x1 + 262144;        // 128*2048*2        = 524288
  float* psum  = parts;              // [c][blk]
  float* psq   = parts + 128 * NBLK; // [c][blk]
  float* st    = parts + 524288;     // stats area        = 2048
  float* sc1 = st + 0,    *sh1 = st + 64;
  float* sc2 = st + 128,  *sh2 = st + 192;
  float* sc3 = st + 256,  *sh3 = st + 384;
  float* t1sc = st + 512, *t1sh = st + 640;
  float* t2sc = st + 768, *t2sh = st + 896;
  float* t3sc = st + 1024, *t3sh = st + 1536;
  float* y1s = st + 2048;            // 2048*128 = 262144
  float* y2s = y1s + 262144;         // 2048*128 = 262144
  float* y3s = y2s + 262144;         // 2048*512 = 1048576
  const size_t BASE = 3284992;                   // end of base layout (floats)
  float* y1pre = w + BASE;                       // 2048*4096 = 8388608
  float* y2pre = y1pre + 8388608;                // 8388608
  float* y3pre = y2pre + 8388608;                // 2048*8192 = 16777216
  const size_t NEED = BASE + 8388608ULL * 2 + 16777216ULL;  // 36.8M floats
  const bool big = ws_size >= NEED * sizeof(float);

  fps_kernel<<<BATCH, 1024, NPTS * sizeof(float4), stream>>>(pos, sp);
  knn_kernel<<<BATCH * MS, 256, 0, stream>>>(pos, x, sp, gf0, sqsel);

  const float invN0 = 1.0f / (float)(NBLK * KNB);  // 1/131072
  if (big) {
    l1_kernel<<<NBLK, 256, 0, stream>>>(gf0, W00, b00, psum, psq, y1pre);
    p_stats<<<64, 256, 0, stream>>>(psum, psq, invN0, g00, be00, sc1, sh1);
    l2_kernel<<<NBLK, 256, 0, stream>>>(y1pre, sc1, sh1, W01, b01, psum, psq, y2pre);
    p_stats<<<64, 256, 0, stream>>>(psum, psq, invN0, g01, be01, sc2, sh2);
    l3_kernel<<<NBLK, 256, 0, stream>>>(y2pre, sc2, sh2, W02, b02, psum, psq, y3pre);
    p_stats<<<128, 256, 0, stream>>>(psum, psq, invN0, g02, be02, sc3, sh3);
    l4_kernel<<<NBLK, 128, 0, stream>>>(y3pre, sc3, sh3, sqsel, x1);
  } else {
    chain_kernel<1><<<NBLK, 256, 0, stream>>>(gf0, W00, b00, W01, b01, W02, b02,
                                              sc1, sh1, sc2, sh2, sc3, sh3, sqsel, psum, psq, x1);
    p_stats<<<64, 256, 0, stream>>>(psum, psq, invN0, g00, be00, sc1, sh1);
    chain_kernel<2><<<NBLK, 256, 0, stream>>>(gf0, W00, b00, W01, b01, W02, b02,
                                              sc1, sh1, sc2, sh2, sc3, sh3, sqsel, psum, psq, x1);
    p_stats<<<64, 256, 0, stream>>>(psum, psq, invN0, g01, be01, sc2, sh2);
    chain_kernel<3><<<NBLK, 256, 0, stream>>>(gf0, W00, b00, W01, b01, W02, b02,
                                              sc1, sh1, sc2, sh2, sc3, sh3, sqsel, psum, psq, x1);
    p_stats<<<128, 256, 0, stream>>>(psum, psq, invN0, g02, be02, sc3, sh3);
    chain_kernel<4><<<NBLK, 256, 0, stream>>>(gf0, W00, b00, W01, b01, W02, b02,
                                              sc1, sh1, sc2, sh2, sc3, sh3, sqsel, psum, psq, x1);
  }

  s1_kernel<<<NBLK, 128, 0, stream>>>(sp, x1, W10, b10, y1s);
  s_stats<<<128, 256, 0, stream>>>(y1s, 128, NBLK, g10, be10, t1sc, t1sh);
  s2_kernel<<<NBLK, 128, 0, stream>>>(y1s, t1sc, t1sh, W11, b11, y2s);
  s_stats<<<128, 256, 0, stream>>>(y2s, 128, NBLK, g11, be11, t2sc, t2sh);
  s3_kernel<<<NBLK, 256, 0, stream>>>(y2s, t2sc, t2sh, W12, b12, y3s);
  s_stats<<<512, 256, 0, stream>>>(y3s, 512, NBLK, g12, be12, t3sc, t3sh);
  final_kernel<<<32, 256, 0, stream>>>(y3s, t3sc, t3sh, (float*)d_out);
}

// Round 12
// 432.154 us; speedup vs baseline: 1.2023x; 1.0193x over previous
//
#include <hip/hip_runtime.h>
#include <cstdint>
#include <cstddef>

#define NPTS 8192
#define BATCH 16
#define MS 128
#define KNB 64
#define NBLK (BATCH * MS)   // 2048

// ---------------- DPP wave reductions (VALU-speed, no LDS crossbar) ----------
__device__ __forceinline__ float dpp_wave_max_f32(float v) {
  v = fmaxf(v, __int_as_float(__builtin_amdgcn_update_dpp((int)0xff800000, __float_as_int(v), 0x111, 0xf, 0xf, false)));
  v = fmaxf(v, __int_as_float(__builtin_amdgcn_update_dpp((int)0xff800000, __float_as_int(v), 0x112, 0xf, 0xf, false)));
  v = fmaxf(v, __int_as_float(__builtin_amdgcn_update_dpp((int)0xff800000, __float_as_int(v), 0x114, 0xf, 0xf, false)));
  v = fmaxf(v, __int_as_float(__builtin_amdgcn_update_dpp((int)0xff800000, __float_as_int(v), 0x118, 0xf, 0xf, false)));
  v = fmaxf(v, __int_as_float(__builtin_amdgcn_update_dpp((int)0xff800000, __float_as_int(v), 0x142, 0xa, 0xf, false)));
  v = fmaxf(v, __int_as_float(__builtin_amdgcn_update_dpp((int)0xff800000, __float_as_int(v), 0x143, 0xc, 0xf, false)));
  return v;  // lane 63
}

__device__ __forceinline__ float dpp_wave_min_f32(float v) {
  v = fminf(v, __int_as_float(__builtin_amdgcn_update_dpp(0x7f800000, __float_as_int(v), 0x111, 0xf, 0xf, false)));
  v = fminf(v, __int_as_float(__builtin_amdgcn_update_dpp(0x7f800000, __float_as_int(v), 0x112, 0xf, 0xf, false)));
  v = fminf(v, __int_as_float(__builtin_amdgcn_update_dpp(0x7f800000, __float_as_int(v), 0x114, 0xf, 0xf, false)));
  v = fminf(v, __int_as_float(__builtin_amdgcn_update_dpp(0x7f800000, __float_as_int(v), 0x118, 0xf, 0xf, false)));
  v = fminf(v, __int_as_float(__builtin_amdgcn_update_dpp(0x7f800000, __float_as_int(v), 0x142, 0xa, 0xf, false)));
  v = fminf(v, __int_as_float(__builtin_amdgcn_update_dpp(0x7f800000, __float_as_int(v), 0x143, 0xc, 0xf, false)));
  return v;  // lane 63
}

__device__ __forceinline__ unsigned dpp_wave_min_u32(unsigned v) {
  unsigned o;
  o = (unsigned)__builtin_amdgcn_update_dpp((int)0xffffffffu, (int)v, 0x111, 0xf, 0xf, false); v = (o < v) ? o : v;
  o = (unsigned)__builtin_amdgcn_update_dpp((int)0xffffffffu, (int)v, 0x112, 0xf, 0xf, false); v = (o < v) ? o : v;
  o = (unsigned)__builtin_amdgcn_update_dpp((int)0xffffffffu, (int)v, 0x114, 0xf, 0xf, false); v = (o < v) ? o : v;
  o = (unsigned)__builtin_amdgcn_update_dpp((int)0xffffffffu, (int)v, 0x118, 0xf, 0xf, false); v = (o < v) ? o : v;
  o = (unsigned)__builtin_amdgcn_update_dpp((int)0xffffffffu, (int)v, 0x142, 0xa, 0xf, false); v = (o < v) ? o : v;
  o = (unsigned)__builtin_amdgcn_update_dpp((int)0xffffffffu, (int)v, 0x143, 0xc, 0xf, false); v = (o < v) ? o : v;
  return v;  // lane 63
}

__device__ __forceinline__ float dpp_row_max_f32(float v) {  // lane 15 of each row
  v = fmaxf(v, __int_as_float(__builtin_amdgcn_update_dpp((int)0xff800000, __float_as_int(v), 0x111, 0xf, 0xf, false)));
  v = fmaxf(v, __int_as_float(__builtin_amdgcn_update_dpp((int)0xff800000, __float_as_int(v), 0x112, 0xf, 0xf, false)));
  v = fmaxf(v, __int_as_float(__builtin_amdgcn_update_dpp((int)0xff800000, __float_as_int(v), 0x114, 0xf, 0xf, false)));
  v = fmaxf(v, __int_as_float(__builtin_amdgcn_update_dpp((int)0xff800000, __float_as_int(v), 0x118, 0xf, 0xf, false)));
  return v;
}

__device__ __forceinline__ unsigned dpp_row_min_u32(unsigned v) {  // lane 15 of each row
  unsigned o;
  o = (unsigned)__builtin_amdgcn_update_dpp((int)0xffffffffu, (int)v, 0x111, 0xf, 0xf, false); v = (o < v) ? o : v;
  o = (unsigned)__builtin_amdgcn_update_dpp((int)0xffffffffu, (int)v, 0x112, 0xf, 0xf, false); v = (o < v) ? o : v;
  o = (unsigned)__builtin_amdgcn_update_dpp((int)0xffffffffu, (int)v, 0x114, 0xf, 0xf, false); v = (o < v) ? o : v;
  o = (unsigned)__builtin_amdgcn_update_dpp((int)0xffffffffu, (int)v, 0x118, 0xf, 0xf, false); v = (o < v) ? o : v;
  return v;
}

// ---------------------------------------------------------------- FPS
// Frozen at its empirical floor (~160us across 6 structures).
#define FPS_STEP(J)                                                        \
  {                                                                        \
    const float4 p = pts4[J * 1024 + t];                                   \
    const float dx = p.x - lx;                                             \
    const float dy = p.y - ly;                                             \
    const float dz = p.z - lz;                                             \
    const float d = dx * dx + dy * dy + dz * dz;                           \
    md##J = fminf(md##J, d);                                               \
  }

#define FPS_RESCAN(J)                                                      \
  if (md##J == wv) best = (unsigned)(J * 1024 + t);

__global__ __launch_bounds__(1024, 4) void fps_kernel(const float* __restrict__ pos,
                                                      float* __restrict__ sp) {
#pragma clang fp contract(off)
  extern __shared__ float4 pts4[];  // 8192 * 16B = 128KB dynamic
  __shared__ float wval[2][16];
  __shared__ unsigned widx[2][16];
  const int b = blockIdx.x;
  const float* P = pos + (size_t)b * NPTS * 3;
  const int t = threadIdx.x;
  const int wave = t >> 6;
  const int lane = t & 63;
  float md0 = 1e10f, md1 = 1e10f, md2 = 1e10f, md3 = 1e10f;
  float md4 = 1e10f, md5 = 1e10f, md6 = 1e10f, md7 = 1e10f;
  for (int i = t; i < NPTS; i += 1024)
    pts4[i] = make_float4(P[i * 3 + 0], P[i * 3 + 1], P[i * 3 + 2], 0.f);
  float lx = P[0], ly = P[1], lz = P[2];
  __syncthreads();
  for (int it = 0; it < MS; ++it) {
    if (t == 0) {
      sp[((size_t)b * MS + it) * 3 + 0] = lx;
      sp[((size_t)b * MS + it) * 3 + 1] = ly;
      sp[((size_t)b * MS + it) * 3 + 2] = lz;
    }
    FPS_STEP(0) FPS_STEP(1) FPS_STEP(2) FPS_STEP(3)
    FPS_STEP(4) FPS_STEP(5) FPS_STEP(6) FPS_STEP(7)
    const float m01 = fmaxf(md0, md1), m23 = fmaxf(md2, md3);
    const float m45 = fmaxf(md4, md5), m67 = fmaxf(md6, md7);
    const float bv = fmaxf(fmaxf(m01, m23), fmaxf(m45, m67));
    const float wv = __int_as_float(
        __builtin_amdgcn_readlane(__float_as_int(dpp_wave_max_f32(bv)), 63));
    unsigned best = 0xffffffffu;
    if (bv == wv) {
      FPS_RESCAN(7) FPS_RESCAN(6) FPS_RESCAN(5) FPS_RESCAN(4)
      FPS_RESCAN(3) FPS_RESCAN(2) FPS_RESCAN(1) FPS_RESCAN(0)
    }
    const unsigned wi =
        (unsigned)__builtin_amdgcn_readlane((int)dpp_wave_min_u32(best), 63);
    const int par = it & 1;
    if (lane == 0) { wval[par][wave] = wv; widx[par][wave] = wi; }
    __syncthreads();
    const float a = wval[par][lane & 15];
    const float M = __int_as_float(
        __builtin_amdgcn_readlane(__float_as_int(dpp_row_max_f32(a)), 15));
    const unsigned c2 = (a == M) ? widx[par][lane & 15] : 0xffffffffu;
    const unsigned idx =
        (unsigned)__builtin_amdgcn_readlane((int)dpp_row_min_u32(c2), 15);
    const float4 c = pts4[idx];
    lx = c.x; ly = c.y; lz = c.z;
  }
}

// ---------------------------------------------------------------- kNN top-64 v3
// Barrier-free per-wave tournament + exact parallel merge.
// Global top-64 (by key = (bits(sq)<<32)|i, ascending) == merge of the 4
// per-wave top-64s (each wave owns 64 columns / 2048 points; any global member
// is within its wave's top-64). Per-wave rounds are wave-local (no barriers):
// consumed tracking via a per-owner-thread 32-bit register mask (no LDS +inf
// writes -> no ordering hazards). sqv stored SWIZZLED (addr = i + (i>>8)) so
// the column rescan (old: 32-way bank conflict) is spread across banks.
// Merge: each of 256 candidates computes rank = r + sum(lower_bound in other
// lists); distinct keys -> permutation; rank<64 scatters -> identical
// ascending selection order to the sequential tournament (proven semantics).
__global__ __launch_bounds__(256) void knn_kernel(const float* __restrict__ pos,
                                                  const float* __restrict__ xf,
                                                  const float* __restrict__ sp,
                                                  float* __restrict__ gf0,
                                                  float* __restrict__ sqsel) {
#pragma clang fp contract(off)
  __shared__ float sqv[NPTS + 32];            // swizzled: addr(i) = i + (i>>8)
  __shared__ unsigned long long wlist[4][KNB];
  __shared__ unsigned long long selk[KNB];
  const int bm = blockIdx.x;
  const int b = bm >> 7;
  const float* P = pos + (size_t)b * NPTS * 3;
  const float sx = sp[bm * 3 + 0], sy = sp[bm * 3 + 1], sz = sp[bm * 3 + 2];
  const float nsp = sx * sx + sy * sy + sz * sz;
  const int t = threadIdx.x;
  const int wave = t >> 6;
  const int lane = t & 63;
  // stage distances + fold per-thread candidate in one pass
  float cv;
  unsigned ci;
  {
    unsigned long long k0 = ~0ULL;
    for (int j = 0; j < 32; ++j) {
      const int i = j * 256 + t;
      const float qx = P[i * 3 + 0], qy = P[i * 3 + 1], qz = P[i * 3 + 2];
      const float npos = qx * qx + qy * qy + qz * qz;
      const float dt = sx * qx + sy * qy + sz * qz;
      float sq = (nsp + npos) - 2.0f * dt;  // matches ||a||^2+||b||^2-2ab order
      sq = fmaxf(sq, 0.0f);
      sqv[i + j] = sq;                      // swizzle: i>>8 == j
      const unsigned long long key =
          ((unsigned long long)__float_as_uint(sq) << 32) | (unsigned)i;
      if (key < k0) k0 = key;
    }
    cv = __uint_as_float((unsigned)(k0 >> 32));
    ci = (unsigned)k0;
  }
  __syncthreads();
  // 64 wave-local rounds (no block barriers)
  unsigned cmask = 0u;  // consumed bits for THIS thread's column
  for (int round = 0; round < KNB; ++round) {
    const float wv = __int_as_float(
        __builtin_amdgcn_readlane(__float_as_int(dpp_wave_min_f32(cv)), 63));
    const unsigned sel = (cv == wv) ? ci : 0xffffffffu;
    const unsigned wi =
        (unsigned)__builtin_amdgcn_readlane((int)dpp_wave_min_u32(sel), 63);
    if (lane == 0)
      wlist[wave][round] =
          ((unsigned long long)__float_as_uint(wv) << 32) | wi;
    const int col = (int)(wi & 255u);       // owner thread id (in this wave)
    const int ownerLane = col & 63;
    const unsigned jsel = wi >> 8;
    if (lane == ownerLane) cmask |= (1u << jsel);  // mark consumed
    const unsigned omask =
        (unsigned)__builtin_amdgcn_readlane((int)cmask, ownerLane);
    // rescan owner's column: lane j in [0,32) reads element j (unless consumed)
    float v = __uint_as_float(0x7f800000u);
    unsigned ii = 0xffffffffu;
    if (lane < 32 && !((omask >> lane) & 1u)) {
      const int i = lane * 256 + col;
      v = sqv[i + lane];                    // swizzle: i>>8 == lane
      ii = (unsigned)i;
    }
    const float mv = __int_as_float(
        __builtin_amdgcn_readlane(__float_as_int(dpp_wave_min_f32(v)), 63));
    const unsigned s2 = (v == mv) ? ii : 0xffffffffu;
    const unsigned mi =
        (unsigned)__builtin_amdgcn_readlane((int)dpp_wave_min_u32(s2), 63);
    if (lane == ownerLane) { cv = mv; ci = mi; }
  }
  __syncthreads();
  // exact merge by parallel ranking (distinct keys -> permutation)
  {
    const int w = wave, r = lane;
    const unsigned long long e = wlist[w][r];
    int rank = r;
#pragma unroll
    for (int w2 = 0; w2 < 4; ++w2) {
      if (w2 == w) continue;
      int lo = 0;
#pragma unroll
      for (int step = 32; step > 0; step >>= 1)
        if (lo + step <= KNB && wlist[w2][lo + step - 1] < e) lo += step;
      rank += lo;
    }
    if (rank < KNB) selk[rank] = e;
  }
  __syncthreads();
  if (t < KNB) {
    const unsigned long long e = selk[t];
    const int i = (int)(e & 0xffffffffu);
    const float* X = xf + (size_t)b * NPTS * 3;
    const size_t base = ((size_t)bm * KNB + t) * 6;
    gf0[base + 0] = P[i * 3 + 0] - sx;
    gf0[base + 1] = P[i * 3 + 1] - sy;
    gf0[base + 2] = P[i * 3 + 2] - sz;
    gf0[base + 3] = X[i * 3 + 0];
    gf0[base + 4] = X[i * 3 + 1];
    gf0[base + 5] = X[i * 3 + 2];
    sqsel[(size_t)bm * KNB + t] = __uint_as_float((unsigned)(e >> 32));
  }
}

// ================================================================ chain
// Single-compute stack with pre-BN activation caching + register-tiled GEMMs.

__global__ __launch_bounds__(256) void l1_kernel(
    const float* __restrict__ gf0, const float* __restrict__ W0,
    const float* __restrict__ B0,
    float* __restrict__ psum, float* __restrict__ psq,
    float* __restrict__ y1pre) {
  __shared__ float in6[64 * 8];
  __shared__ float wbuf[384];
  __shared__ float out[64 * 65];
  const int blk = blockIdx.x;
  const int t = threadIdx.x;
  const float* G = gf0 + (size_t)blk * 384;
  for (int i = t; i < 384; i += 256) in6[(i / 6) * 8 + (i % 6)] = G[i];
  for (int i = t; i < 384; i += 256) wbuf[i] = W0[i];
  __syncthreads();
  const int r = t >> 2;
  const int c0 = (t & 3) * 16;
  float acc[16];
#pragma unroll
  for (int j = 0; j < 16; ++j) acc[j] = B0[c0 + j];
  for (int cin = 0; cin < 6; ++cin) {
    const float a = in6[r * 8 + cin];
#pragma unroll
    for (int j = 0; j < 16; ++j) acc[j] = fmaf(a, wbuf[cin * 64 + c0 + j], acc[j]);
  }
#pragma unroll
  for (int j = 0; j < 16; ++j) out[r * 65 + c0 + j] = acc[j];
  __syncthreads();
  if (t < 64) {
    float s = 0.f, q = 0.f;
    for (int r2 = 0; r2 < 64; ++r2) { const float v = out[r2 * 65 + t]; s += v; q += v * v; }
    psum[(size_t)t * NBLK + blk] = s;
    psq[(size_t)t * NBLK + blk] = q;
  }
  float* Y = y1pre + (size_t)blk * 4096;
  for (int i = t; i < 4096; i += 256) Y[i] = out[(i >> 6) * 65 + (i & 63)];
}

__global__ __launch_bounds__(256) void l2_kernel(
    const float* __restrict__ ypre, const float* __restrict__ sc,
    const float* __restrict__ sh, const float* __restrict__ W1,
    const float* __restrict__ B1,
    float* __restrict__ psum, float* __restrict__ psq,
    float* __restrict__ yout) {
  __shared__ float As[64 * 68];
  __shared__ float Bs[64 * 64];
  __shared__ float out[64 * 68];
  const int blk = blockIdx.x;
  const int t = threadIdx.x;
  const float* Y = ypre + (size_t)blk * 4096;
  for (int i = t; i < 4096; i += 256) {
    const int c = i & 63;
    As[(i >> 6) * 68 + c] = fmaxf(fmaf(Y[i], sc[c], sh[c]), 0.f);
  }
  for (int i = t; i < 4096; i += 256) Bs[i] = W1[i];
  __syncthreads();
  const int tr = t >> 4;
  const int tc4 = (t & 15) * 4;
  float acc[4][4];
#pragma unroll
  for (int s = 0; s < 4; ++s)
#pragma unroll
    for (int j = 0; j < 4; ++j) acc[s][j] = B1[tc4 + j];
  for (int k0 = 0; k0 < 64; k0 += 4) {
    float4 av[4];
#pragma unroll
    for (int s = 0; s < 4; ++s)
      av[s] = *reinterpret_cast<const float4*>(&As[(tr + 16 * s) * 68 + k0]);
#pragma unroll
    for (int kk = 0; kk < 4; ++kk) {
      const float4 bv = *reinterpret_cast<const float4*>(&Bs[(k0 + kk) * 64 + tc4]);
#pragma unroll
      for (int s = 0; s < 4; ++s) {
        const float a = (kk == 0) ? av[s].x : (kk == 1) ? av[s].y
                       : (kk == 2) ? av[s].z : av[s].w;
        acc[s][0] = fmaf(a, bv.x, acc[s][0]);
        acc[s][1] = fmaf(a, bv.y, acc[s][1]);
        acc[s][2] = fmaf(a, bv.z, acc[s][2]);
        acc[s][3] = fmaf(a, bv.w, acc[s][3]);
      }
    }
  }
#pragma unroll
  for (int s = 0; s < 4; ++s) {
    float4 o;
    o.x = acc[s][0]; o.y = acc[s][1]; o.z = acc[s][2]; o.w = acc[s][3];
    *reinterpret_cast<float4*>(&out[(tr + 16 * s) * 68 + tc4]) = o;
  }
  __syncthreads();
  if (t < 64) {
    float s = 0.f, q = 0.f;
    for (int r2 = 0; r2 < 64; ++r2) { const float v = out[r2 * 68 + t]; s += v; q += v * v; }
    psum[(size_t)t * NBLK + blk] = s;
    psq[(size_t)t * NBLK + blk] = q;
  }
  float* O = yout + (size_t)blk * 4096;
  for (int i = t; i < 4096; i += 256) O[i] = out[(i >> 6) * 68 + (i & 63)];
}

__global__ __launch_bounds__(256) void l3_kernel(
    const float* __restrict__ ypre, const float* __restrict__ sc,
    const float* __restrict__ sh, const float* __restrict__ W2,
    const float* __restrict__ B2,
    float* __restrict__ psum, float* __restrict__ psq,
    float* __restrict__ yout) {
  __shared__ float As[64 * 68];
  __shared__ float Bs[64 * 64];
  __shared__ float out[64 * 68];
  const int blk = blockIdx.x;
  const int t = threadIdx.x;
  const float* Y = ypre + (size_t)blk * 4096;
  for (int i = t; i < 4096; i += 256) {
    const int c = i & 63;
    As[(i >> 6) * 68 + c] = fmaxf(fmaf(Y[i], sc[c], sh[c]), 0.f);
  }
  const int tr = t >> 4;
  const int tc4 = (t & 15) * 4;
  for (int hc = 0; hc < 2; ++hc) {
    __syncthreads();
    for (int i = t; i < 4096; i += 256)
      Bs[i] = W2[(i >> 6) * 128 + hc * 64 + (i & 63)];
    __syncthreads();
    float acc[4][4];
#pragma unroll
    for (int s = 0; s < 4; ++s)
#pragma unroll
      for (int j = 0; j < 4; ++j) acc[s][j] = B2[hc * 64 + tc4 + j];
    for (int k0 = 0; k0 < 64; k0 += 4) {
      float4 av[4];
#pragma unroll
      for (int s = 0; s < 4; ++s)
        av[s] = *reinterpret_cast<const float4*>(&As[(tr + 16 * s) * 68 + k0]);
#pragma unroll
      for (int kk = 0; kk < 4; ++kk) {
        const float4 bv = *reinterpret_cast<const float4*>(&Bs[(k0 + kk) * 64 + tc4]);
#pragma unroll
        for (int s = 0; s < 4; ++s) {
          const float a = (kk == 0) ? av[s].x : (kk == 1) ? av[s].y
                         : (kk == 2) ? av[s].z : av[s].w;
          acc[s][0] = fmaf(a, bv.x, acc[s][0]);
          acc[s][1] = fmaf(a, bv.y, acc[s][1]);
          acc[s][2] = fmaf(a, bv.z, acc[s][2]);
          acc[s][3] = fmaf(a, bv.w, acc[s][3]);
        }
      }
    }
#pragma unroll
    for (int s = 0; s < 4; ++s) {
      float4 o;
      o.x = acc[s][0]; o.y = acc[s][1]; o.z = acc[s][2]; o.w = acc[s][3];
      *reinterpret_cast<float4*>(&out[(tr + 16 * s) * 68 + tc4]) = o;
    }
    __syncthreads();
    if (t < 64) {
      float s = 0.f, q = 0.f;
      for (int r2 = 0; r2 < 64; ++r2) { const float v = out[r2 * 68 + t]; s += v; q += v * v; }
      psum[(size_t)(hc * 64 + t) * NBLK + blk] = s;
      psq[(size_t)(hc * 64 + t) * NBLK + blk] = q;
    }
    float* O = yout + (size_t)blk * 8192;
    for (int i = t; i < 4096; i += 256)
      O[(i >> 6) * 128 + hc * 64 + (i & 63)] = out[(i >> 6) * 68 + (i & 63)];
  }
}

__global__ __launch_bounds__(128) void l4_kernel(
    const float* __restrict__ y3pre, const float* __restrict__ sc3,
    const float* __restrict__ sh3, const float* __restrict__ sqsel,
    float* __restrict__ x1) {
  __shared__ float sqs[64];
  const int blk = blockIdx.x;
  const int t = threadIdx.x;
  if (t < 64) sqs[t] = sqsel[(size_t)blk * 64 + t];
  __syncthreads();
  const float scv = sc3[t], shv = sh3[t];
  const float* Y = y3pre + (size_t)blk * 8192;
  float mx = -1e8f;
  for (int r = 0; r < 64; ++r) {
    const float act = fmaxf(fmaf(Y[r * 128 + t], scv, shv), 0.f);
    const float v = (sqs[r] <= 0.16f) ? act : -1e8f;
    mx = fmaxf(mx, v);
  }
  x1[(size_t)blk * 128 + t] = mx;
}

// Parallel deterministic stats reduce: one block per channel, f64 LDS tree.
__global__ __launch_bounds__(256) void p_stats(const float* __restrict__ psum,
                                               const float* __restrict__ psq,
                                               float invN,
                                               const float* __restrict__ g,
                                               const float* __restrict__ be,
                                               float* __restrict__ sc,
                                               float* __restrict__ sh) {
  const int c = blockIdx.x;
  const int t = threadIdx.x;
  double s = 0.0, q = 0.0;
  for (int k = t; k < NBLK; k += 256) {
    s += (double)psum[(size_t)c * NBLK + k];
    q += (double)psq[(size_t)c * NBLK + k];
  }
  __shared__ double ss[256], qq[256];
  ss[t] = s;
  qq[t] = q;
  __syncthreads();
  for (int st = 128; st > 0; st >>= 1) {
    if (t < st) { ss[t] += ss[t + st]; qq[t] += qq[t + st]; }
    __syncthreads();
  }
  if (t == 0) {
    const double mean = ss[0] * (double)invN;
    double var = qq[0] * (double)invN - mean * mean;
    if (var < 0.0) var = 0.0;
    const float scl = (float)((double)g[c] / sqrt(var + 1e-5));
    sc[c] = scl;
    sh[c] = be[c] - (float)mean * scl;
  }
}

// ---------------------------------------------------------------- stage 1
__global__ __launch_bounds__(128) void s1_kernel(const float* __restrict__ sp,
                                                 const float* __restrict__ x1,
                                                 const float* __restrict__ W,
                                                 const float* __restrict__ bia,
                                                 float* __restrict__ y1) {
  __shared__ float row[132];
  const int rowid = blockIdx.x;
  const int t = threadIdx.x;
  if (t < 3) row[t] = sp[(size_t)rowid * 3 + t];
  row[3 + t] = x1[(size_t)rowid * 128 + t];
  __syncthreads();
  float acc = bia[t];
  for (int cin = 0; cin < 131; ++cin) acc = fmaf(row[cin], W[(size_t)cin * 128 + t], acc);
  y1[(size_t)rowid * 128 + t] = acc;
}

__global__ __launch_bounds__(128) void s2_kernel(const float* __restrict__ y1,
                                                 const float* __restrict__ sc, const float* __restrict__ sh,
                                                 const float* __restrict__ W, const float* __restrict__ bia,
                                                 float* __restrict__ y2) {
  __shared__ float row[128];
  const int rowid = blockIdx.x;
  const int t = threadIdx.x;
  row[t] = fmaxf(fmaf(y1[(size_t)rowid * 128 + t], sc[t], sh[t]), 0.f);
  __syncthreads();
  float acc = bia[t];
  for (int cin = 0; cin < 128; ++cin) acc = fmaf(row[cin], W[(size_t)cin * 128 + t], acc);
  y2[(size_t)rowid * 128 + t] = acc;
}

__global__ __launch_bounds__(256) void s3_kernel(const float* __restrict__ y2,
                                                 const float* __restrict__ sc, const float* __restrict__ sh,
                                                 const float* __restrict__ W, const float* __restrict__ bia,
                                                 float* __restrict__ y3) {
  __shared__ float row[128];
  const int rowid = blockIdx.x;
  const int t = threadIdx.x;
  if (t < 128) row[t] = fmaxf(fmaf(y2[(size_t)rowid * 128 + t], sc[t], sh[t]), 0.f);
  __syncthreads();
  for (int h = 0; h < 2; ++h) {
    const int c = h * 256 + t;
    float acc = bia[c];
    for (int cin = 0; cin < 128; ++cin) acc = fmaf(row[cin], W[(size_t)cin * 512 + c], acc);
    y3[(size_t)rowid * 512 + c] = acc;
  }
}

__global__ __launch_bounds__(256) void s_stats(const float* __restrict__ y, int C, int rows,
                                               const float* __restrict__ g, const float* __restrict__ be,
                                               float* __restrict__ sc, float* __restrict__ sh) {
  const int c = blockIdx.x;
  const int t = threadIdx.x;
  double s = 0.0, q = 0.0;
  for (int r2 = t; r2 < rows; r2 += 256) {
    const double v = (double)y[(size_t)r2 * C + c];
    s += v;
    q += v * v;
  }
  __shared__ double ss[256], qq[256];
  ss[t] = s;
  qq[t] = q;
  __syncthreads();
  for (int st = 128; st > 0; st >>= 1) {
    if (t < st) { ss[t] += ss[t + st]; qq[t] += qq[t + st]; }
    __syncthreads();
  }
  if (t == 0) {
    const double mean = ss[0] / rows;
    double var = qq[0] / rows - mean * mean;
    if (var < 0.0) var = 0.0;
    const float scl = (float)((double)g[c] / sqrt(var + 1e-5));
    sc[c] = scl;
    sh[c] = be[c] - (float)mean * scl;
  }
}

__global__ __launch_bounds__(256) void final_kernel(const float* __restrict__ y3,
                                                    const float* __restrict__ sc, const float* __restrict__ sh,
                                                    float* __restrict__ out) {
  const int gid = blockIdx.x * 256 + threadIdx.x;  // 8192 = 16 batches x 512 ch
  const int b = gid >> 9;
  const int c = gid & 511;
  const float scv = sc[c], shv = sh[c];
  float mx = -3.402823466e+38f;
  for (int m = 0; m < 128; ++m) {
    const float v = fmaxf(fmaf(y3[((size_t)(b * 128 + m)) * 512 + c], scv, shv), 0.f);
    mx = fmaxf(mx, v);
  }
  out[gid] = mx;
  if (gid < 48) out[8192 + gid] = 0.f;  // pos_out zeros
}

extern "C" void kernel_launch(void* const* d_in, const int* in_sizes, int n_in,
                              void* d_out, int out_size, void* d_ws, size_t ws_size,
                              hipStream_t stream) {
  const float* x    = (const float*)d_in[0];
  const float* pos  = (const float*)d_in[1];
  const float* W00  = (const float*)d_in[2];
  const float* b00  = (const float*)d_in[3];
  const float* g00  = (const float*)d_in[4];
  const float* be00 = (const float*)d_in[5];
  const float* W01  = (const float*)d_in[6];
  const float* b01  = (const float*)d_in[7];
  const float* g01  = (const float*)d_in[8];
  const float* be01 = (const float*)d_in[9];
  const float* W02  = (const float*)d_in[10];
  const float* b02  = (const float*)d_in[11];
  const float* g02  = (const float*)d_in[12];
  const float* be02 = (const float*)d_in[13];
  const float* W10  = (const float*)d_in[14];
  const float* b10  = (const float*)d_in[15];
  const float* g10  = (const float*)d_in[16];
  const float* be10 = (const float*)d_in[17];
  const float* W11  = (const float*)d_in[18];
  const float* b11  = (const float*)d_in[19];
  const float* g11  = (const float*)d_in[20];
  const float* be11 = (const float*)d_in[21];
  const float* W12  = (const float*)d_in[22];
  const float* b12  = (const float*)d_in[23];
  const float* g12  = (const float*)d_in[24];
  const float* be12 = (const float*)d_in[25];

  float* w = (float*)d_ws;
  float* sp    = w;                  // 16*128*3          = 6144
  float* gf0   = sp + 6144;          // 16*128*64*6       = 786432
  float* sqsel = gf0 + 786432;       // 16*128*64         = 131072
  float* x1    = sqsel + 131072;     // 16*128*128        = 262144
  float* parts = x1 + 262144;        // 128*2048*2        = 524288
  float* psum  = parts;              // [c][blk]
  float* psq   = parts + 128 * NBLK; // [c][blk]
  float* st    = parts + 524288;     // stats area        = 2048
  float* sc1 = st + 0,    *sh1 = st + 64;
  float* sc2 = st + 128,  *sh2 = st + 192;
  float* sc3 = st + 256,  *sh3 = st + 384;
  float* t1sc = st + 512, *t1sh = st + 640;
  float* t2sc = st + 768, *t2sh = st + 896;
  float* t3sc = st + 1024, *t3sh = st + 1536;
  float* y1s = st + 2048;            // 2048*128 = 262144
  float* y2s = y1s + 262144;         // 2048*128 = 262144
  float* y3s = y2s + 262144;         // 2048*512 = 1048576
  const size_t BASE = 3284992;                   // end of base layout (floats)
  float* y1pre = w + BASE;                       // 2048*4096 = 8388608
  float* y2pre = y1pre + 8388608;                // 8388608
  float* y3pre = y2pre + 8388608;                // 2048*8192 = 16777216
  const size_t NEED = BASE + 8388608ULL * 2 + 16777216ULL;  // 36.8M floats
  // (big-path layout; harness ws is expected to satisfy this, as in round 10)
  (void)NEED;

  fps_kernel<<<BATCH, 1024, NPTS * sizeof(float4), stream>>>(pos, sp);
  knn_kernel<<<BATCH * MS, 256, 0, stream>>>(pos, x, sp, gf0, sqsel);

  const float invN0 = 1.0f / (float)(NBLK * KNB);  // 1/131072
  l1_kernel<<<NBLK, 256, 0, stream>>>(gf0, W00, b00, psum, psq, y1pre);
  p_stats<<<64, 256, 0, stream>>>(psum, psq, invN0, g00, be00, sc1, sh1);
  l2_kernel<<<NBLK, 256, 0, stream>>>(y1pre, sc1, sh1, W01, b01, psum, psq, y2pre);
  p_stats<<<64, 256, 0, stream>>>(psum, psq, invN0, g01, be01, sc2, sh2);
  l3_kernel<<<NBLK, 256, 0, stream>>>(y2pre, sc2, sh2, W02, b02, psum, psq, y3pre);
  p_stats<<<128, 256, 0, stream>>>(psum, psq, invN0, g02, be02, sc3, sh3);
  l4_kernel<<<NBLK, 128, 0, stream>>>(y3pre, sc3, sh3, sqsel, x1);

  s1_kernel<<<NBLK, 128, 0, stream>>>(sp, x1, W10, b10, y1s);
  s_stats<<<128, 256, 0, stream>>>(y1s, 128, NBLK, g10, be10, t1sc, t1sh);
  s2_kernel<<<NBLK, 128, 0, stream>>>(y1s, t1sc, t1sh, W11, b11, y2s);
  s_stats<<<128, 256, 0, stream>>>(y2s, 128, NBLK, g11, be11, t2sc, t2sh);
  s3_kernel<<<NBLK, 256, 0, stream>>>(y2s, t2sc, t2sh, W12, b12, y3s);
  s_stats<<<512, 256, 0, stream>>>(y3s, 512, NBLK, g12, be12, t3sc, t3sh);
  final_kernel<<<32, 256, 0, stream>>>(y3s, t3sc, t3sh, (float*)d_out);
}